// Round 2
// baseline (25825.821 us; speedup 1.0000x reference)
//
#include <hip/hip_runtime.h>
#include <hip/hip_bf16.h>
#include <math.h>

typedef __hip_bfloat16 bf16;

#define NATT 11
#define Bb 8
#define Ss 512
#define Dd 768
#define Hh 256

__device__ __forceinline__ void stf(float* p, float v) { *p = v; }
__device__ __forceinline__ void stf(bf16* p, float v) { *p = __float2bfloat16(v); }

__device__ __forceinline__ float blo(unsigned u) { return __uint_as_float(u << 16); }
__device__ __forceinline__ float bhi(unsigned u) { return __uint_as_float(u & 0xffff0000u); }

// dtype-flexible input load: flag==1 -> fp32, flag==0 -> bf16
__device__ __forceinline__ float ldg_any(const void* base, long idx, int flag) {
  if (flag) return ((const float*)base)[idx];
  return __bfloat162float(((const bf16*)base)[idx]);
}

// ---------- dtype probe: flags[0]=float dtype (1=fp32,0=bf16), flags[1]=labels int64? ----------
__global__ __launch_bounds__(64) void probe_kernel(
    const unsigned short* __restrict__ sequ, const unsigned* __restrict__ labu,
    int* __restrict__ flags)
{
  int t = threadIdx.x;
  int wild = 0;
#pragma unroll
  for (int i = 0; i < 4; i++) {
    unsigned short v = sequ[t + i * 64];
    int e = (v >> 7) & 0xFF;   // bf16 exponent field
    if (e < 90 || e > 160) wild++;   // genuine bf16 ~N(0,1): never wild
  }
  int nzodd = 0;
#pragma unroll
  for (int i = 0; i < 2; i++) {
    unsigned w = labu[(t + i * 64) * 2 + 1];
    if (w != 0) nzodd++;
  }
  for (int o = 32; o > 0; o >>= 1) {
    wild  += __shfl_down(wild, o);
    nzodd += __shfl_down(nzodd, o);
  }
  if (t == 0) {
    flags[0] = (wild > 32) ? 1 : 0;   // many wild exponents => data is fp32
    flags[1] = (nzodd == 0) ? 1 : 0;  // all odd u32 words zero => int64 labels
  }
}

// ---------- build am (emb gather), seq->fp32, qmask ----------
__global__ __launch_bounds__(256) void build_am_kernel(
    const void* __restrict__ labels, const void* __restrict__ emb,
    const void* __restrict__ seq, float* __restrict__ am,
    float* __restrict__ seqf, float* __restrict__ qmask,
    const int* __restrict__ flags)
{
  int fflag = flags[0], lflag = flags[1];
  int row = blockIdx.x;            // 0..B*S-1
  long lab = lflag ? (long)((const long long*)labels)[row]
                   : (long)((const int*)labels)[row];
  int t = threadIdx.x;
  float s = 0.f;
#pragma unroll
  for (int i = 0; i < 3; i++) {
    int e = t + i * 256;
    float v = ldg_any(emb, lab * Dd + e, fflag);
    am[(long)row * Dd + e] = v;
    s += v;
    seqf[(long)row * Dd + e] = ldg_any(seq, (long)row * Dd + e, fflag);
  }
  for (int o = 32; o > 0; o >>= 1) s += __shfl_down(s, o);
  __shared__ float red[4];
  if ((t & 63) == 0) red[t >> 6] = s;
  __syncthreads();
  if (t == 0) {
    float tot = red[0] + red[1] + red[2] + red[3];
    qmask[row] = (tot != 0.f) ? 1.f : 0.f;
  }
}

// ---------- tiled GEMM, C = epilogue(scale * A@W) ----------
// NN: A[M,K] fp32, W[K,N] (dtype by flag, element offset wOff), C[M,N] (OT).
template <typename OT>
__global__ __launch_bounds__(256) void gemm_nn(
    const float* __restrict__ A, const void* __restrict__ W, long wOff,
    const void* __restrict__ bias, long bOff, OT* __restrict__ C,
    int M, int N, int K, long sA, long sW, long sC,
    float scale, int relu,
    const float* __restrict__ add1, const float* __restrict__ add2,
    const int* __restrict__ flags, int wIsInput)
{
  int fflag = flags[0];
  int wflag = wIsInput ? fflag : 1;   // ws buffers are always fp32
  __shared__ float As[16][66];
  __shared__ float Bs[16][66];
  int bz = blockIdx.z;
  A += bz * sA; C += bz * sC;
  long wBase = wOff + (long)bz * sW;
  if (add1) add1 += bz * sC;
  if (add2) add2 += bz * sC;
  int bn = blockIdx.x * 64;
  int bm = blockIdx.y * 64;
  int tid = threadIdx.x;
  int tx4 = (tid & 15) * 4;
  int ty4 = (tid >> 4) * 4;
  float acc[4][4] = {};
  for (int k0 = 0; k0 < K; k0 += 16) {
#pragma unroll
    for (int i = 0; i < 4; i++) {
      int idx = tid + i * 256;
      int m = idx >> 4, kk = idx & 15;
      As[kk][m] = A[(long)(bm + m) * K + k0 + kk];
      int kw = idx >> 6, nw = idx & 63;
      Bs[kw][nw] = ldg_any(W, wBase + (long)(k0 + kw) * N + bn + nw, wflag);
    }
    __syncthreads();
#pragma unroll
    for (int kk = 0; kk < 16; kk++) {
      float av[4], bv[4];
#pragma unroll
      for (int i = 0; i < 4; i++) av[i] = As[kk][ty4 + i];
#pragma unroll
      for (int j = 0; j < 4; j++) bv[j] = Bs[kk][tx4 + j];
#pragma unroll
      for (int i = 0; i < 4; i++)
#pragma unroll
        for (int j = 0; j < 4; j++) acc[i][j] += av[i] * bv[j];
    }
    __syncthreads();
  }
#pragma unroll
  for (int i = 0; i < 4; i++) {
    int m = bm + ty4 + i;
#pragma unroll
    for (int j = 0; j < 4; j++) {
      int n = bn + tx4 + j;
      float v = acc[i][j] * scale;
      if (bias) v += ldg_any(bias, bOff + n, fflag);
      if (relu) v = fmaxf(v, 0.f);
      long off = (long)m * N + n;
      if (add1) v += add1[off];
      if (add2) v += add2[off];
      stf(C + off, v);
    }
  }
}

// NT: A[M,K] fp32, Bm[N,K] (dtype by flag, element offset wOff) used transposed.
template <typename OT>
__global__ __launch_bounds__(256) void gemm_nt(
    const float* __restrict__ A, const void* __restrict__ Bm, long wOff,
    const void* __restrict__ bias, long bOff, OT* __restrict__ C,
    int M, int N, int K, long sA, long sB, long sC,
    float scale, int relu,
    const float* __restrict__ add1, const float* __restrict__ add2,
    const int* __restrict__ flags, int wIsInput)
{
  int fflag = flags[0];
  int wflag = wIsInput ? fflag : 1;
  __shared__ float As[16][66];
  __shared__ float Bs[16][66];
  int bz = blockIdx.z;
  A += bz * sA; C += bz * sC;
  long wBase = wOff + (long)bz * sB;
  if (add1) add1 += bz * sC;
  if (add2) add2 += bz * sC;
  int bn = blockIdx.x * 64;
  int bm = blockIdx.y * 64;
  int tid = threadIdx.x;
  int tx4 = (tid & 15) * 4;
  int ty4 = (tid >> 4) * 4;
  float acc[4][4] = {};
  for (int k0 = 0; k0 < K; k0 += 16) {
#pragma unroll
    for (int i = 0; i < 4; i++) {
      int idx = tid + i * 256;
      int m = idx >> 4, kk = idx & 15;
      As[kk][m] = A[(long)(bm + m) * K + k0 + kk];
      Bs[kk][m] = ldg_any(Bm, wBase + (long)(bn + m) * K + k0 + kk, wflag);
    }
    __syncthreads();
#pragma unroll
    for (int kk = 0; kk < 16; kk++) {
      float av[4], bv[4];
#pragma unroll
      for (int i = 0; i < 4; i++) av[i] = As[kk][ty4 + i];
#pragma unroll
      for (int j = 0; j < 4; j++) bv[j] = Bs[kk][tx4 + j];
#pragma unroll
      for (int i = 0; i < 4; i++)
#pragma unroll
        for (int j = 0; j < 4; j++) acc[i][j] += av[i] * bv[j];
    }
    __syncthreads();
  }
#pragma unroll
  for (int i = 0; i < 4; i++) {
    int m = bm + ty4 + i;
#pragma unroll
    for (int j = 0; j < 4; j++) {
      int n = bn + tx4 + j;
      float v = acc[i][j] * scale;
      if (bias) v += ldg_any(bias, bOff + n, fflag);
      if (relu) v = fmaxf(v, 0.f);
      long off = (long)m * N + n;
      if (add1) v += add1[off];
      if (add2) v += add2[off];
      stf(C + off, v);
    }
  }
}

// ---------- softmax over last dim (512) + post-softmax query mask ----------
__global__ __launch_bounds__(256) void softmax_mask_kernel(
    float* __restrict__ scores, const float* __restrict__ qmask)
{
  long row = blockIdx.x;            // b*S+q
  float* p = scores + row * Ss;
  int t = threadIdx.x;
  float e0 = p[t], e1 = p[t + 256];
  float m = fmaxf(e0, e1);
  for (int o = 32; o > 0; o >>= 1) m = fmaxf(m, __shfl_down(m, o));
  __shared__ float red[4];
  if ((t & 63) == 0) red[t >> 6] = m;
  __syncthreads();
  float M4 = fmaxf(fmaxf(red[0], red[1]), fmaxf(red[2], red[3]));
  float v0 = __expf(e0 - M4), v1 = __expf(e1 - M4);
  float s = v0 + v1;
  for (int o = 32; o > 0; o >>= 1) s += __shfl_down(s, o);
  __syncthreads();
  if ((t & 63) == 0) red[t >> 6] = s;
  __syncthreads();
  float S4 = red[0] + red[1] + red[2] + red[3];
  float inv = qmask[row] / S4;
  p[t] = v0 * inv;
  p[t + 256] = v1 * inv;
}

// ---------- GRU recurrence: one block per (dir, sequence) ----------
__global__ __launch_bounds__(256) void gru_kernel(
    const bf16* __restrict__ xp,    // [2][88][S][3H] ws bf16, includes bih
    const void* __restrict__ Whh,   // [2][3H][H] input dtype
    const void* __restrict__ bhh,   // [2][3H] input dtype
    float* __restrict__ hbuf,       // [2][88][H]
    const int* __restrict__ flags)
{
  int flag = flags[0];
  __shared__ float hs[256];
  int idx = blockIdx.x;
  int dir = idx / 88, n = idx - dir * 88;
  int c = threadIdx.x;
  const bf16* xpb = xp + ((long)(dir * 88 + n)) * Ss * Dd;
  float bh_r = ldg_any(bhh, dir * Dd + c, flag);
  float bh_z = ldg_any(bhh, dir * Dd + 256 + c, flag);
  float bh_n = ldg_any(bhh, dir * Dd + 512 + c, flag);
  const bf16*  wb16 = (const bf16*)Whh + (long)dir * Dd * Hh;
  const float* wbf  = (const float*)Whh + (long)dir * Dd * Hh;
  const uint4*  wr16 = (const uint4*)(wb16 + (long)c * Hh);
  const uint4*  wz16 = (const uint4*)(wb16 + (long)(c + 256) * Hh);
  const uint4*  wn16 = (const uint4*)(wb16 + (long)(c + 512) * Hh);
  const float4* wrf  = (const float4*)(wbf + (long)c * Hh);
  const float4* wzf  = (const float4*)(wbf + (long)(c + 256) * Hh);
  const float4* wnf  = (const float4*)(wbf + (long)(c + 512) * Hh);
  hs[c] = 0.f;
  __syncthreads();
  const float4* hp4 = (const float4*)hs;
  for (int tt = 0; tt < Ss; tt++) {
    int t = dir ? (Ss - 1 - tt) : tt;
    const bf16* xt = xpb + (long)t * Dd;
    float xr = __bfloat162float(xt[c]);
    float xz = __bfloat162float(xt[c + 256]);
    float xn = __bfloat162float(xt[c + 512]);
    float hold = hs[c];
    float ar = 0.f, az = 0.f, an = 0.f;
    if (flag) {
#pragma unroll 8
      for (int j4 = 0; j4 < 64; j4++) {
        float4 w0 = wrf[j4], w1 = wzf[j4], w2 = wnf[j4];
        float4 h = hp4[j4];
        ar += w0.x * h.x + w0.y * h.y + w0.z * h.z + w0.w * h.w;
        az += w1.x * h.x + w1.y * h.y + w1.z * h.z + w1.w * h.w;
        an += w2.x * h.x + w2.y * h.y + w2.z * h.z + w2.w * h.w;
      }
    } else {
#pragma unroll 4
      for (int j8 = 0; j8 < 32; j8++) {
        uint4 ur = wr16[j8], uz = wz16[j8], un = wn16[j8];
        float4 h0 = hp4[j8 * 2], h1 = hp4[j8 * 2 + 1];
        ar += blo(ur.x) * h0.x + bhi(ur.x) * h0.y + blo(ur.y) * h0.z + bhi(ur.y) * h0.w
            + blo(ur.z) * h1.x + bhi(ur.z) * h1.y + blo(ur.w) * h1.z + bhi(ur.w) * h1.w;
        az += blo(uz.x) * h0.x + bhi(uz.x) * h0.y + blo(uz.y) * h0.z + bhi(uz.y) * h0.w
            + blo(uz.z) * h1.x + bhi(uz.z) * h1.y + blo(uz.w) * h1.z + bhi(uz.w) * h1.w;
        an += blo(un.x) * h0.x + bhi(un.x) * h0.y + blo(un.y) * h0.z + bhi(un.y) * h0.w
            + blo(un.z) * h1.x + bhi(un.z) * h1.y + blo(un.w) * h1.z + bhi(un.w) * h1.w;
      }
    }
    float r = 1.f / (1.f + __expf(-(xr + ar + bh_r)));
    float z = 1.f / (1.f + __expf(-(xz + az + bh_z)));
    float nn = tanhf(xn + r * (an + bh_n));
    float hnew = (1.f - z) * nn + z * hold;
    __syncthreads();
    hs[c] = hnew;
    __syncthreads();
  }
  hbuf[((long)(dir * 88 + n)) * Hh + c] = hs[c];
}

// ---------- final head: sigmoid(concat(hf,hb) @ W1 + b1) ----------
__global__ __launch_bounds__(256) void head_kernel(
    const float* __restrict__ hbuf, const void* __restrict__ W1,
    const void* __restrict__ b1, void* __restrict__ out,
    const int* __restrict__ flags)
{
  int flag = flags[0];
  int n = blockIdx.x;   // 0..87, n = k*B + b
  int c = threadIdx.x;  // 256
  float v = hbuf[(long)n * Hh + c] * ldg_any(W1, c, flag)
          + hbuf[(long)(88 + n) * Hh + c] * ldg_any(W1, 256 + c, flag);
  for (int o = 32; o > 0; o >>= 1) v += __shfl_down(v, o);
  __shared__ float red[4];
  if ((c & 63) == 0) red[c >> 6] = v;
  __syncthreads();
  if (c == 0) {
    float s = red[0] + red[1] + red[2] + red[3] + ldg_any(b1, 0, flag);
    float sig = 1.f / (1.f + __expf(-s));
    int k = n / Bb, b = n - k * Bb;
    int o = b * NATT + k;
    if (flag) ((float*)out)[o] = sig;
    else      stf((bf16*)out + o, sig);
  }
}

extern "C" void kernel_launch(void* const* d_in, const int* in_sizes, int n_in,
                              void* d_out, int out_size, void* d_ws, size_t ws_size,
                              hipStream_t stream) {
  const void* labels = d_in[0];
  const void* seq  = d_in[1];
  const void* emb  = d_in[2];
  const void* Wq   = d_in[3];
  const void* bq   = d_in[4];
  const void* Wk   = d_in[5];
  const void* bk   = d_in[6];
  const void* Wv   = d_in[7];
  const void* bv   = d_in[8];
  const void* Wih  = d_in[9];
  const void* Whh  = d_in[10];
  const void* bih  = d_in[11];
  const void* bhh  = d_in[12];
  const void* W1   = d_in[13];
  const void* b1   = d_in[14];

  char* p = (char*)d_ws;
  size_t off = 0;
  auto alloc = [&](size_t bytes) -> void* {
    void* r = p + off; off += (bytes + 255) & ~(size_t)255; return r;
  };
  int*   flags = (int*)alloc(2 * sizeof(int));
  float* am    = (float*)alloc(4096UL * 768 * 4);
  float* seqf  = (float*)alloc(4096UL * 768 * 4);
  float* qmask = (float*)alloc(4096UL * 4);
  float* Qk    = (float*)alloc(4096UL * 768 * 4);
  float* Kk    = (float*)alloc(4096UL * 768 * 4);
  float* Vk    = (float*)alloc(4096UL * 768 * 4);
  float* sc    = (float*)alloc(8UL * 512 * 512 * 4);
  float* elout = (float*)alloc(4096UL * 768 * 4);
  bf16*  xpb   = (bf16*)alloc(2UL * 88 * 512 * 768 * 2);
  float* hbuf  = (float*)alloc(2UL * 88 * 256 * 4);
  if (off > ws_size) return;

  probe_kernel<<<1, 64, 0, stream>>>((const unsigned short*)seq,
                                     (const unsigned*)labels, flags);
  build_am_kernel<<<4096, 256, 0, stream>>>(labels, emb, seq, am, seqf, qmask, flags);

  const float scl = 1.f / sqrtf(768.f);
  for (int k = 0; k < NATT; k++) {
    long wo = (long)k * 768 * 768;  // element offset of branch-k weight
    long bo = (long)k * 768;        // element offset of branch-k bias
    gemm_nn<float><<<dim3(12, 64, 1), 256, 0, stream>>>(
        am, Wq, wo, bq, bo, Qk, 4096, 768, 768, 0, 0, 0,
        1.f, 1, nullptr, nullptr, flags, 1);
    gemm_nn<float><<<dim3(12, 64, 1), 256, 0, stream>>>(
        seqf, Wk, wo, bk, bo, Kk, 4096, 768, 768, 0, 0, 0,
        1.f, 1, nullptr, nullptr, flags, 1);
    gemm_nn<float><<<dim3(12, 64, 1), 256, 0, stream>>>(
        seqf, Wv, wo, bv, bo, Vk, 4096, 768, 768, 0, 0, 0,
        1.f, 1, nullptr, nullptr, flags, 1);
    // scores = Q @ K^T / sqrt(D), batched over b
    gemm_nt<float><<<dim3(8, 8, 8), 256, 0, stream>>>(
        Qk, Kk, 0, nullptr, 0, sc, 512, 512, 768,
        512L * 768, 512L * 768, 512L * 512, scl, 0, nullptr, nullptr, flags, 0);
    softmax_mask_kernel<<<4096, 256, 0, stream>>>(sc, qmask);
    // elout = attn @ V + am + seq, batched over b
    gemm_nn<float><<<dim3(12, 8, 8), 256, 0, stream>>>(
        sc, Vk, 0, nullptr, 0, elout, 512, 768, 512,
        512L * 512, 512L * 768, 512L * 768, 1.f, 0, am, seqf, flags, 0);
    // xp[dir] slice for this k: elout @ Wih^T + bih  -> bf16
    for (int d2 = 0; d2 < 2; d2++) {
      gemm_nt<bf16><<<dim3(12, 64, 1), 256, 0, stream>>>(
          elout, Wih, (long)d2 * 768 * 768, bih, (long)d2 * 768,
          xpb + ((long)d2 * 88 + (long)k * 8) * 512 * 768,
          4096, 768, 768, 0, 0, 0, 1.f, 0, nullptr, nullptr, flags, 1);
    }
  }
  gru_kernel<<<176, 256, 0, stream>>>(xpb, Whh, bhh, hbuf, flags);
  head_kernel<<<88, 256, 0, stream>>>(hbuf, W1, b1, (bf16*)d_out, flags);
}

// Round 3
// 9772.896 us; speedup vs baseline: 2.6426x; 2.6426x over previous
//
#include <hip/hip_runtime.h>
#include <hip/hip_bf16.h>
#include <hip/hip_fp16.h>
#include <math.h>

typedef __hip_bfloat16 bf16;

#define NATT 11
#define Bb 8
#define Ss 512
#define Dd 768
#define Hh 256

__device__ __forceinline__ void stf(float* p, float v) { *p = v; }
__device__ __forceinline__ void stf(bf16* p, float v) { *p = __float2bfloat16(v); }

__device__ __forceinline__ float blo(unsigned u) { return __uint_as_float(u << 16); }
__device__ __forceinline__ float bhi(unsigned u) { return __uint_as_float(u & 0xffff0000u); }
__device__ __forceinline__ float b2f(unsigned short u) { return __uint_as_float(((unsigned)u) << 16); }

// dtype-flexible input load: flag==1 -> fp32, flag==0 -> bf16
__device__ __forceinline__ float ldg_any(const void* base, long idx, int flag) {
  if (flag) return ((const float*)base)[idx];
  return __bfloat162float(((const bf16*)base)[idx]);
}

// pack two floats to fp16x2 bits
__device__ __forceinline__ unsigned packh2(float a, float b) {
  __half2 hh = __floats2half2_rn(a, b);
  return __builtin_bit_cast(unsigned, hh);
}

typedef _Float16 f16x2 __attribute__((ext_vector_type(2)));

// fp16x2 dot product accumulating fp32
__device__ __forceinline__ float dot2u(unsigned a, unsigned b, float c) {
#if __has_builtin(__builtin_amdgcn_fdot2)
  return __builtin_amdgcn_fdot2(__builtin_bit_cast(f16x2, a),
                                __builtin_bit_cast(f16x2, b), c, false);
#else
  __half2 ah = __builtin_bit_cast(__half2, a);
  __half2 bh = __builtin_bit_cast(__half2, b);
  float2 af = __half22float2(ah), bf = __half22float2(bh);
  return c + af.x * bf.x + af.y * bf.y;
#endif
}

// ---------- dtype probe: flags[0]=float dtype (1=fp32,0=bf16), flags[1]=labels int64? ----------
__global__ __launch_bounds__(64) void probe_kernel(
    const unsigned short* __restrict__ sequ, const unsigned* __restrict__ labu,
    int* __restrict__ flags)
{
  int t = threadIdx.x;
  int wild = 0;
#pragma unroll
  for (int i = 0; i < 4; i++) {
    unsigned short v = sequ[t + i * 64];
    int e = (v >> 7) & 0xFF;
    if (e < 90 || e > 160) wild++;
  }
  int nzodd = 0;
#pragma unroll
  for (int i = 0; i < 2; i++) {
    unsigned w = labu[(t + i * 64) * 2 + 1];
    if (w != 0) nzodd++;
  }
  for (int o = 32; o > 0; o >>= 1) {
    wild  += __shfl_down(wild, o);
    nzodd += __shfl_down(nzodd, o);
  }
  if (t == 0) {
    flags[0] = (wild > 32) ? 1 : 0;
    flags[1] = (nzodd == 0) ? 1 : 0;
  }
}

// ---------- build am (emb gather), seq->fp32, qmask ----------
__global__ __launch_bounds__(256) void build_am_kernel(
    const void* __restrict__ labels, const void* __restrict__ emb,
    const void* __restrict__ seq, float* __restrict__ am,
    float* __restrict__ seqf, float* __restrict__ qmask,
    const int* __restrict__ flags)
{
  int fflag = flags[0], lflag = flags[1];
  int row = blockIdx.x;
  long lab = lflag ? (long)((const long long*)labels)[row]
                   : (long)((const int*)labels)[row];
  int t = threadIdx.x;
  float s = 0.f;
#pragma unroll
  for (int i = 0; i < 3; i++) {
    int e = t + i * 256;
    float v = ldg_any(emb, lab * Dd + e, fflag);
    am[(long)row * Dd + e] = v;
    s += v;
    seqf[(long)row * Dd + e] = ldg_any(seq, (long)row * Dd + e, fflag);
  }
  for (int o = 32; o > 0; o >>= 1) s += __shfl_down(s, o);
  __shared__ float red[4];
  if ((t & 63) == 0) red[t >> 6] = s;
  __syncthreads();
  if (t == 0) {
    float tot = red[0] + red[1] + red[2] + red[3];
    qmask[row] = (tot != 0.f) ? 1.f : 0.f;
  }
}

// ---------- tiled GEMM, C = epilogue(scale * A@W) ----------
template <typename OT>
__global__ __launch_bounds__(256) void gemm_nn(
    const float* __restrict__ A, const void* __restrict__ W, long wOff,
    const void* __restrict__ bias, long bOff, OT* __restrict__ C,
    int M, int N, int K, long sA, long sW, long sC,
    float scale, int relu,
    const float* __restrict__ add1, const float* __restrict__ add2,
    const int* __restrict__ flags, int wIsInput)
{
  int fflag = flags[0];
  int wflag = wIsInput ? fflag : 1;
  __shared__ float As[16][66];
  __shared__ float Bs[16][66];
  int bz = blockIdx.z;
  A += bz * sA; C += bz * sC;
  long wBase = wOff + (long)bz * sW;
  if (add1) add1 += bz * sC;
  if (add2) add2 += bz * sC;
  int bn = blockIdx.x * 64;
  int bm = blockIdx.y * 64;
  int tid = threadIdx.x;
  int tx4 = (tid & 15) * 4;
  int ty4 = (tid >> 4) * 4;
  float acc[4][4] = {};
  for (int k0 = 0; k0 < K; k0 += 16) {
#pragma unroll
    for (int i = 0; i < 4; i++) {
      int idx = tid + i * 256;
      int m = idx >> 4, kk = idx & 15;
      As[kk][m] = A[(long)(bm + m) * K + k0 + kk];
      int kw = idx >> 6, nw = idx & 63;
      Bs[kw][nw] = ldg_any(W, wBase + (long)(k0 + kw) * N + bn + nw, wflag);
    }
    __syncthreads();
#pragma unroll
    for (int kk = 0; kk < 16; kk++) {
      float av[4], bv[4];
#pragma unroll
      for (int i = 0; i < 4; i++) av[i] = As[kk][ty4 + i];
#pragma unroll
      for (int j = 0; j < 4; j++) bv[j] = Bs[kk][tx4 + j];
#pragma unroll
      for (int i = 0; i < 4; i++)
#pragma unroll
        for (int j = 0; j < 4; j++) acc[i][j] += av[i] * bv[j];
    }
    __syncthreads();
  }
#pragma unroll
  for (int i = 0; i < 4; i++) {
    int m = bm + ty4 + i;
#pragma unroll
    for (int j = 0; j < 4; j++) {
      int n = bn + tx4 + j;
      float v = acc[i][j] * scale;
      if (bias) v += ldg_any(bias, bOff + n, fflag);
      if (relu) v = fmaxf(v, 0.f);
      long off = (long)m * N + n;
      if (add1) v += add1[off];
      if (add2) v += add2[off];
      stf(C + off, v);
    }
  }
}

template <typename OT>
__global__ __launch_bounds__(256) void gemm_nt(
    const float* __restrict__ A, const void* __restrict__ Bm, long wOff,
    const void* __restrict__ bias, long bOff, OT* __restrict__ C,
    int M, int N, int K, long sA, long sB, long sC,
    float scale, int relu,
    const float* __restrict__ add1, const float* __restrict__ add2,
    const int* __restrict__ flags, int wIsInput)
{
  int fflag = flags[0];
  int wflag = wIsInput ? fflag : 1;
  __shared__ float As[16][66];
  __shared__ float Bs[16][66];
  int bz = blockIdx.z;
  A += bz * sA; C += bz * sC;
  long wBase = wOff + (long)bz * sB;
  if (add1) add1 += bz * sC;
  if (add2) add2 += bz * sC;
  int bn = blockIdx.x * 64;
  int bm = blockIdx.y * 64;
  int tid = threadIdx.x;
  int tx4 = (tid & 15) * 4;
  int ty4 = (tid >> 4) * 4;
  float acc[4][4] = {};
  for (int k0 = 0; k0 < K; k0 += 16) {
#pragma unroll
    for (int i = 0; i < 4; i++) {
      int idx = tid + i * 256;
      int m = idx >> 4, kk = idx & 15;
      As[kk][m] = A[(long)(bm + m) * K + k0 + kk];
      Bs[kk][m] = ldg_any(Bm, wBase + (long)(bn + m) * K + k0 + kk, wflag);
    }
    __syncthreads();
#pragma unroll
    for (int kk = 0; kk < 16; kk++) {
      float av[4], bv[4];
#pragma unroll
      for (int i = 0; i < 4; i++) av[i] = As[kk][ty4 + i];
#pragma unroll
      for (int j = 0; j < 4; j++) bv[j] = Bs[kk][tx4 + j];
#pragma unroll
      for (int i = 0; i < 4; i++)
#pragma unroll
        for (int j = 0; j < 4; j++) acc[i][j] += av[i] * bv[j];
    }
    __syncthreads();
  }
#pragma unroll
  for (int i = 0; i < 4; i++) {
    int m = bm + ty4 + i;
#pragma unroll
    for (int j = 0; j < 4; j++) {
      int n = bn + tx4 + j;
      float v = acc[i][j] * scale;
      if (bias) v += ldg_any(bias, bOff + n, fflag);
      if (relu) v = fmaxf(v, 0.f);
      long off = (long)m * N + n;
      if (add1) v += add1[off];
      if (add2) v += add2[off];
      stf(C + off, v);
    }
  }
}

// ---------- softmax over last dim (512) + post-softmax query mask ----------
__global__ __launch_bounds__(256) void softmax_mask_kernel(
    float* __restrict__ scores, const float* __restrict__ qmask)
{
  long row = blockIdx.x;
  float* p = scores + row * Ss;
  int t = threadIdx.x;
  float e0 = p[t], e1 = p[t + 256];
  float m = fmaxf(e0, e1);
  for (int o = 32; o > 0; o >>= 1) m = fmaxf(m, __shfl_down(m, o));
  __shared__ float red[4];
  if ((t & 63) == 0) red[t >> 6] = m;
  __syncthreads();
  float M4 = fmaxf(fmaxf(red[0], red[1]), fmaxf(red[2], red[3]));
  float v0 = __expf(e0 - M4), v1 = __expf(e1 - M4);
  float s = v0 + v1;
  for (int o = 32; o > 0; o >>= 1) s += __shfl_down(s, o);
  __syncthreads();
  if ((t & 63) == 0) red[t >> 6] = s;
  __syncthreads();
  float S4 = red[0] + red[1] + red[2] + red[3];
  float inv = qmask[row] / S4;
  p[t] = v0 * inv;
  p[t + 256] = v1 * inv;
}

// ---------- GRU recurrence, weights register-resident as packed fp16 ----------
// 512 threads: thread (c = tid&255, q = tid>>8) holds Whh rows {r,z,n}[c],
// h-columns [128q, 128q+128) as 192 fp16x2-packed VGPRs. h lives in LDS as
// fp16; partial dots reduced across q via LDS; gate math fp32; the combiner
// thread carries its h[c] in fp32 for the z*h path. xp double-buffered in LDS,
// prefetched one step ahead.
__global__ __launch_bounds__(512, 2) void gru_kernel(
    const bf16* __restrict__ xp,    // [2][88][S][3H] bf16 ws, includes bih
    const void* __restrict__ Whh,   // [2][3H][H] input dtype
    const void* __restrict__ bhh,   // [2][3H] input dtype
    float* __restrict__ hbuf,       // [2][88][H]
    const int* __restrict__ flags)
{
  int flag = flags[0];
  int idx = blockIdx.x;
  int dir = idx / 88, n = idx - dir * 88;
  int tid = threadIdx.x;
  int c = tid & 255;
  int q = tid >> 8;   // 0 or 1
  const unsigned short* xpb =
      (const unsigned short*)xp + ((long)(dir * 88 + n)) * Ss * Dd;

  // ---- load weights into registers (fp16x2-packed) ----
  unsigned w[3][64];
#pragma unroll
  for (int g = 0; g < 3; g++) {
    long rowBase = ((long)dir * Dd + g * 256 + c) * Hh + q * 128;
    if (flag) {
      const float4* s4 = (const float4*)((const float*)Whh + rowBase);
#pragma unroll
      for (int i = 0; i < 32; i++) {
        float4 v = s4[i];
        w[g][2 * i]     = packh2(v.x, v.y);
        w[g][2 * i + 1] = packh2(v.z, v.w);
      }
    } else {
      const uint4* s4 = (const uint4*)((const bf16*)Whh + rowBase);
#pragma unroll
      for (int i = 0; i < 16; i++) {
        uint4 v = s4[i];
        w[g][4 * i]     = packh2(blo(v.x), bhi(v.x));
        w[g][4 * i + 1] = packh2(blo(v.y), bhi(v.y));
        w[g][4 * i + 2] = packh2(blo(v.z), bhi(v.z));
        w[g][4 * i + 3] = packh2(blo(v.w), bhi(v.w));
      }
    }
  }

  __shared__ __align__(16) unsigned short hsh[256];   // h as fp16
  __shared__ float partial[2][3][256];
  __shared__ unsigned short xsh[2][768];              // raw bf16 bits, dbuf
  float bh[3] = {0.f, 0.f, 0.f};
  float hprev = 0.f;
  if (tid < 256) hsh[tid] = 0;
  if (q == 0) {
#pragma unroll
    for (int g = 0; g < 3; g++) bh[g] = ldg_any(bhh, dir * Dd + g * 256 + c, flag);
    int t0 = dir ? (Ss - 1) : 0;
#pragma unroll
    for (int g = 0; g < 3; g++) xsh[0][g * 256 + c] = xpb[(long)t0 * Dd + g * 256 + c];
  }
  __syncthreads();

  const uint4* hp = (const uint4*)(hsh + q * 128);   // 16 uint4 = 128 halfs
  for (int tt = 0; tt < Ss; tt++) {
    // prefetch next step's x (overlaps with the dot loop below)
    unsigned short xnr = 0, xnz = 0, xnn = 0;
    if (q == 0) {
      int ttn = (tt < Ss - 1) ? tt + 1 : tt;
      int tn = dir ? (Ss - 1 - ttn) : ttn;
      const unsigned short* xrow = xpb + (long)tn * Dd;
      xnr = xrow[c]; xnz = xrow[256 + c]; xnn = xrow[512 + c];
    }
    float ar = 0.f, az = 0.f, an = 0.f;
#pragma unroll
    for (int jj = 0; jj < 16; jj++) {
      uint4 hv = hp[jj];
      ar = dot2u(w[0][4 * jj],     hv.x, ar);
      ar = dot2u(w[0][4 * jj + 1], hv.y, ar);
      ar = dot2u(w[0][4 * jj + 2], hv.z, ar);
      ar = dot2u(w[0][4 * jj + 3], hv.w, ar);
      az = dot2u(w[1][4 * jj],     hv.x, az);
      az = dot2u(w[1][4 * jj + 1], hv.y, az);
      az = dot2u(w[1][4 * jj + 2], hv.z, az);
      az = dot2u(w[1][4 * jj + 3], hv.w, az);
      an = dot2u(w[2][4 * jj],     hv.x, an);
      an = dot2u(w[2][4 * jj + 1], hv.y, an);
      an = dot2u(w[2][4 * jj + 2], hv.z, an);
      an = dot2u(w[2][4 * jj + 3], hv.w, an);
    }
    partial[q][0][c] = ar;
    partial[q][1][c] = az;
    partial[q][2][c] = an;
    if (q == 0) {
      int nb = (tt + 1) & 1;
      xsh[nb][c] = xnr; xsh[nb][256 + c] = xnz; xsh[nb][512 + c] = xnn;
    }
    __syncthreads();
    if (q == 0) {
      int cb = tt & 1;
      float agr = partial[0][0][c] + partial[1][0][c] + bh[0];
      float agz = partial[0][1][c] + partial[1][1][c] + bh[1];
      float agn = partial[0][2][c] + partial[1][2][c] + bh[2];
      float xr = b2f(xsh[cb][c]);
      float xz = b2f(xsh[cb][256 + c]);
      float xn = b2f(xsh[cb][512 + c]);
      float r = 1.f / (1.f + __expf(-(xr + agr)));
      float z = 1.f / (1.f + __expf(-(xz + agz)));
      float nn2 = tanhf(xn + r * agn);
      float hnew = (1.f - z) * nn2 + z * hprev;
      hprev = hnew;
      __half hh = __float2half(hnew);
      hsh[c] = __builtin_bit_cast(unsigned short, hh);
    }
    __syncthreads();
  }
  if (q == 0) hbuf[((long)(dir * 88 + n)) * Hh + c] = hprev;
}

// ---------- final head: sigmoid(concat(hf,hb) @ W1 + b1) ----------
__global__ __launch_bounds__(256) void head_kernel(
    const float* __restrict__ hbuf, const void* __restrict__ W1,
    const void* __restrict__ b1, void* __restrict__ out,
    const int* __restrict__ flags)
{
  int flag = flags[0];
  int n = blockIdx.x;   // 0..87, n = k*B + b
  int c = threadIdx.x;
  float v = hbuf[(long)n * Hh + c] * ldg_any(W1, c, flag)
          + hbuf[(long)(88 + n) * Hh + c] * ldg_any(W1, 256 + c, flag);
  for (int o = 32; o > 0; o >>= 1) v += __shfl_down(v, o);
  __shared__ float red[4];
  if ((c & 63) == 0) red[c >> 6] = v;
  __syncthreads();
  if (c == 0) {
    float s = red[0] + red[1] + red[2] + red[3] + ldg_any(b1, 0, flag);
    float sig = 1.f / (1.f + __expf(-s));
    int k = n / Bb, b = n - k * Bb;
    int o = b * NATT + k;
    if (flag) ((float*)out)[o] = sig;
    else      stf((bf16*)out + o, sig);
  }
}

extern "C" void kernel_launch(void* const* d_in, const int* in_sizes, int n_in,
                              void* d_out, int out_size, void* d_ws, size_t ws_size,
                              hipStream_t stream) {
  const void* labels = d_in[0];
  const void* seq  = d_in[1];
  const void* emb  = d_in[2];
  const void* Wq   = d_in[3];
  const void* bq   = d_in[4];
  const void* Wk   = d_in[5];
  const void* bk   = d_in[6];
  const void* Wv   = d_in[7];
  const void* bv   = d_in[8];
  const void* Wih  = d_in[9];
  const void* Whh  = d_in[10];
  const void* bih  = d_in[11];
  const void* bhh  = d_in[12];
  const void* W1   = d_in[13];
  const void* b1   = d_in[14];

  char* p = (char*)d_ws;
  size_t off = 0;
  auto alloc = [&](size_t bytes) -> void* {
    void* r = p + off; off += (bytes + 255) & ~(size_t)255; return r;
  };
  int*   flags = (int*)alloc(2 * sizeof(int));
  float* am    = (float*)alloc(4096UL * 768 * 4);
  float* seqf  = (float*)alloc(4096UL * 768 * 4);
  float* qmask = (float*)alloc(4096UL * 4);
  float* Qk    = (float*)alloc(4096UL * 768 * 4);
  float* Kk    = (float*)alloc(4096UL * 768 * 4);
  float* Vk    = (float*)alloc(4096UL * 768 * 4);
  float* sc    = (float*)alloc(8UL * 512 * 512 * 4);
  float* elout = (float*)alloc(4096UL * 768 * 4);
  bf16*  xpb   = (bf16*)alloc(2UL * 88 * 512 * 768 * 2);
  float* hbuf  = (float*)alloc(2UL * 88 * 256 * 4);
  if (off > ws_size) return;

  probe_kernel<<<1, 64, 0, stream>>>((const unsigned short*)seq,
                                     (const unsigned*)labels, flags);
  build_am_kernel<<<4096, 256, 0, stream>>>(labels, emb, seq, am, seqf, qmask, flags);

  const float scl = 1.f / sqrtf(768.f);
  for (int k = 0; k < NATT; k++) {
    long wo = (long)k * 768 * 768;
    long bo = (long)k * 768;
    gemm_nn<float><<<dim3(12, 64, 1), 256, 0, stream>>>(
        am, Wq, wo, bq, bo, Qk, 4096, 768, 768, 0, 0, 0,
        1.f, 1, nullptr, nullptr, flags, 1);
    gemm_nn<float><<<dim3(12, 64, 1), 256, 0, stream>>>(
        seqf, Wk, wo, bk, bo, Kk, 4096, 768, 768, 0, 0, 0,
        1.f, 1, nullptr, nullptr, flags, 1);
    gemm_nn<float><<<dim3(12, 64, 1), 256, 0, stream>>>(
        seqf, Wv, wo, bv, bo, Vk, 4096, 768, 768, 0, 0, 0,
        1.f, 1, nullptr, nullptr, flags, 1);
    gemm_nt<float><<<dim3(8, 8, 8), 256, 0, stream>>>(
        Qk, Kk, 0, nullptr, 0, sc, 512, 512, 768,
        512L * 768, 512L * 768, 512L * 512, scl, 0, nullptr, nullptr, flags, 0);
    softmax_mask_kernel<<<4096, 256, 0, stream>>>(sc, qmask);
    gemm_nn<float><<<dim3(12, 8, 8), 256, 0, stream>>>(
        sc, Vk, 0, nullptr, 0, elout, 512, 768, 512,
        512L * 512, 512L * 768, 512L * 768, 1.f, 0, am, seqf, flags, 0);
    for (int d2 = 0; d2 < 2; d2++) {
      gemm_nt<bf16><<<dim3(12, 64, 1), 256, 0, stream>>>(
          elout, Wih, (long)d2 * 768 * 768, bih, (long)d2 * 768,
          xpb + ((long)d2 * 88 + (long)k * 8) * 512 * 768,
          4096, 768, 768, 0, 0, 0, 1.f, 0, nullptr, nullptr, flags, 1);
    }
  }
  gru_kernel<<<176, 512, 0, stream>>>(xpb, Whh, bhh, hbuf, flags);
  head_kernel<<<88, 256, 0, stream>>>(hbuf, W1, b1, (bf16*)d_out, flags);
}

// Round 4
// 3115.025 us; speedup vs baseline: 8.2907x; 3.1373x over previous
//
#include <hip/hip_runtime.h>
#include <hip/hip_bf16.h>
#include <hip/hip_fp16.h>
#include <math.h>

typedef __hip_bfloat16 bf16;
typedef __attribute__((ext_vector_type(8))) short short8;
typedef __attribute__((ext_vector_type(4))) float f32x4;

#define NATT 11
#define Bb 8
#define Ss 512
#define Dd 768
#define Hh 256

__device__ __forceinline__ void stf(float* p, float v) { *p = v; }
__device__ __forceinline__ void stf(bf16* p, float v) { *p = __float2bfloat16(v); }

__device__ __forceinline__ float blo(unsigned u) { return __uint_as_float(u << 16); }
__device__ __forceinline__ float bhi(unsigned u) { return __uint_as_float(u & 0xffff0000u); }
__device__ __forceinline__ float b2f(unsigned short u) { return __uint_as_float(((unsigned)u) << 16); }

// dtype-flexible input load: flag==1 -> fp32, flag==0 -> bf16
__device__ __forceinline__ float ldg_any(const void* base, long idx, int flag) {
  if (flag) return ((const float*)base)[idx];
  return __bfloat162float(((const bf16*)base)[idx]);
}

__device__ __forceinline__ unsigned packh2(float a, float b) {
  __half2 hh = __floats2half2_rn(a, b);
  return __builtin_bit_cast(unsigned, hh);
}

typedef _Float16 f16x2 __attribute__((ext_vector_type(2)));

__device__ __forceinline__ float dot2u(unsigned a, unsigned b, float c) {
#if __has_builtin(__builtin_amdgcn_fdot2)
  return __builtin_amdgcn_fdot2(__builtin_bit_cast(f16x2, a),
                                __builtin_bit_cast(f16x2, b), c, false);
#else
  __half2 ah = __builtin_bit_cast(__half2, a);
  __half2 bh = __builtin_bit_cast(__half2, b);
  float2 af = __half22float2(ah), bf = __half22float2(bh);
  return c + af.x * bf.x + af.y * bf.y;
#endif
}

// ---------- dtype probe ----------
__global__ __launch_bounds__(64) void probe_kernel(
    const unsigned short* __restrict__ sequ, const unsigned* __restrict__ labu,
    int* __restrict__ flags)
{
  int t = threadIdx.x;
  int wild = 0;
#pragma unroll
  for (int i = 0; i < 4; i++) {
    unsigned short v = sequ[t + i * 64];
    int e = (v >> 7) & 0xFF;
    if (e < 90 || e > 160) wild++;
  }
  int nzodd = 0;
#pragma unroll
  for (int i = 0; i < 2; i++) {
    unsigned w = labu[(t + i * 64) * 2 + 1];
    if (w != 0) nzodd++;
  }
  for (int o = 32; o > 0; o >>= 1) {
    wild  += __shfl_down(wild, o);
    nzodd += __shfl_down(nzodd, o);
  }
  if (t == 0) {
    flags[0] = (wild > 32) ? 1 : 0;
    flags[1] = (nzodd == 0) ? 1 : 0;
  }
}

// ---------- build am/seq as bf16 + qmask ----------
__global__ __launch_bounds__(256) void build_am_kernel(
    const void* __restrict__ labels, const void* __restrict__ emb,
    const void* __restrict__ seq, bf16* __restrict__ amb,
    bf16* __restrict__ seqb, float* __restrict__ qmask,
    const int* __restrict__ flags)
{
  int fflag = flags[0], lflag = flags[1];
  int row = blockIdx.x;
  long lab = lflag ? (long)((const long long*)labels)[row]
                   : (long)((const int*)labels)[row];
  int t = threadIdx.x;
  float s = 0.f;
#pragma unroll
  for (int i = 0; i < 3; i++) {
    int e = t + i * 256;
    float v = ldg_any(emb, lab * Dd + e, fflag);
    amb[(long)row * Dd + e] = __float2bfloat16(v);
    s += v;
    seqb[(long)row * Dd + e] = __float2bfloat16(ldg_any(seq, (long)row * Dd + e, fflag));
  }
  for (int o = 32; o > 0; o >>= 1) s += __shfl_down(s, o);
  __shared__ float red[4];
  if ((t & 63) == 0) red[t >> 6] = s;
  __syncthreads();
  if (t == 0) {
    float tot = red[0] + red[1] + red[2] + red[3];
    qmask[row] = (tot != 0.f) ? 1.f : 0.f;
  }
}

// ---------- transpose Wq/Wk/Wv branch-k slices to [N][K] bf16 ----------
__global__ __launch_bounds__(256) void transpose3_kernel(
    const void* __restrict__ Wq, const void* __restrict__ Wk,
    const void* __restrict__ Wv, long off,
    bf16* __restrict__ WqT, bf16* __restrict__ WkT, bf16* __restrict__ WvT,
    const int* __restrict__ flags)
{
  int flag = flags[0];
  __shared__ float tile[32][33];
  int z = blockIdx.z;
  const void* src = (z == 0) ? Wq : (z == 1) ? Wk : Wv;
  bf16* dst = (z == 0) ? WqT : (z == 1) ? WkT : WvT;
  int k0 = blockIdx.y * 32, n0 = blockIdx.x * 32;
  int tx = threadIdx.x & 31, ty = threadIdx.x >> 5;  // 32 x 8
#pragma unroll
  for (int i = 0; i < 4; i++)
    tile[ty + i * 8][tx] = ldg_any(src, off + (long)(k0 + ty + i * 8) * Dd + n0 + tx, flag);
  __syncthreads();
#pragma unroll
  for (int i = 0; i < 4; i++)
    dst[(long)(n0 + ty + i * 8) * Dd + k0 + tx] = __float2bfloat16(tile[tx][ty + i * 8]);
}

// ---------- convert Wih to bf16 (already NT-natural: [3H][D], K contiguous) ----------
__global__ __launch_bounds__(256) void convert_kernel(
    const void* __restrict__ src, bf16* __restrict__ dst, long n,
    const int* __restrict__ flags)
{
  int flag = flags[0];
  long i = (long)blockIdx.x * 256 + threadIdx.x;
  if (i < n) dst[i] = __float2bfloat16(ldg_any(src, i, flag));
}

// ---------- NT bf16 MFMA GEMM: C = epi(scale*A@B^T) ----------
// A[M,K] bf16 (ldA,sA), B[N,K] bf16 (ldB,sB). cMode: 0=bf16, 1=bf16 transposed
// (C[col*ldC+row]), 2=fp32. res1/res2: bf16 residuals, C-layout (mode 0 only).
__global__ __launch_bounds__(256, 2) void gemm_mfma(
    const bf16* __restrict__ A, long ldA, long sA,
    const bf16* __restrict__ B, long ldB, long sB,
    const void* __restrict__ bias, long bOff,
    void* __restrict__ C, long ldC, long sC, int cMode,
    const bf16* __restrict__ res1, const bf16* __restrict__ res2,
    int M, int N, int K, float scale, int relu,
    const int* __restrict__ flags)
{
  int fflag = flags[0];
  __shared__ bf16 As[128][40];   // pad 32 -> 40 (80B rows: 16B-aligned, banks spread)
  __shared__ bf16 Bs[128][40];
  int bz = blockIdx.z;
  const bf16* Ab = A + (long)bz * sA;
  const bf16* Bbp = B + (long)bz * sB;
  long cBase = (long)bz * sC;
  int bm = blockIdx.y * 128, bn = blockIdx.x * 128;
  int tid = threadIdx.x;
  int lane = tid & 63, w = tid >> 6;
  int mo = (w & 1) * 64, no = (w >> 1) * 64;
  int l15 = lane & 15, q4 = lane >> 4;
  int sr = tid >> 2;          // staging row 0..63
  int sseg = (tid & 3) * 8;   // k segment (8 bf16 = 16B)

  f32x4 acc[4][4];
#pragma unroll
  for (int i = 0; i < 4; i++)
#pragma unroll
    for (int j = 0; j < 4; j++)
#pragma unroll
      for (int r = 0; r < 4; r++) acc[i][j][r] = 0.f;

  for (int k0 = 0; k0 < K; k0 += 32) {
#pragma unroll
    for (int h = 0; h < 2; h++) {
      int row = sr + h * 64;
      uint4 av = *(const uint4*)(Ab + (long)(bm + row) * ldA + k0 + sseg);
      uint4 bv = *(const uint4*)(Bbp + (long)(bn + row) * ldB + k0 + sseg);
      *(uint4*)&As[row][sseg] = av;
      *(uint4*)&Bs[row][sseg] = bv;
    }
    __syncthreads();
    short8 af[4], bfv[4];
#pragma unroll
    for (int i = 0; i < 4; i++)
      af[i] = *(const short8*)&As[mo + i * 16 + l15][q4 * 8];
#pragma unroll
    for (int j = 0; j < 4; j++)
      bfv[j] = *(const short8*)&Bs[no + j * 16 + l15][q4 * 8];
#pragma unroll
    for (int i = 0; i < 4; i++)
#pragma unroll
      for (int j = 0; j < 4; j++)
        acc[i][j] = __builtin_amdgcn_mfma_f32_16x16x32_bf16(af[i], bfv[j], acc[i][j], 0, 0, 0);
    __syncthreads();
  }

  // epilogue: C/D layout col=lane&15, row=q4*4+reg  [m89-verified]
  float bsv[4];
#pragma unroll
  for (int j = 0; j < 4; j++) {
    int colg = bn + no + j * 16 + l15;
    bsv[j] = bias ? ldg_any(bias, bOff + colg, fflag) : 0.f;
  }
#pragma unroll
  for (int i = 0; i < 4; i++) {
#pragma unroll
    for (int j = 0; j < 4; j++) {
      int colg = bn + no + j * 16 + l15;
      if (cMode == 1) {
        int rowg0 = bm + mo + i * 16 + q4 * 4;
        ushort4 pk;
        unsigned short tmp[4];
#pragma unroll
        for (int r = 0; r < 4; r++) {
          float v = acc[i][j][r] * scale + bsv[j];
          if (relu) v = fmaxf(v, 0.f);
          tmp[r] = __builtin_bit_cast(unsigned short, __float2bfloat16(v));
        }
        pk.x = tmp[0]; pk.y = tmp[1]; pk.z = tmp[2]; pk.w = tmp[3];
        *(ushort4*)((bf16*)C + cBase + (long)colg * ldC + rowg0) = pk;
      } else {
#pragma unroll
        for (int r = 0; r < 4; r++) {
          int rowg = bm + mo + i * 16 + q4 * 4 + r;
          float v = acc[i][j][r] * scale + bsv[j];
          if (relu) v = fmaxf(v, 0.f);
          long off2 = (long)rowg * ldC + colg;
          if (res1) v += __bfloat162float(res1[cBase + off2]);
          if (res2) v += __bfloat162float(res2[cBase + off2]);
          if (cMode == 2) ((float*)C)[cBase + off2] = v;
          else            ((bf16*)C)[cBase + off2] = __float2bfloat16(v);
        }
      }
    }
  }
}

// ---------- softmax over last dim (512) + query mask -> bf16 ----------
__global__ __launch_bounds__(256) void softmax_mask_kernel(
    const float* __restrict__ scores, const float* __restrict__ qmask,
    bf16* __restrict__ attnb)
{
  long row = blockIdx.x;
  const float* p = scores + row * Ss;
  int t = threadIdx.x;
  float e0 = p[t], e1 = p[t + 256];
  float m = fmaxf(e0, e1);
  for (int o = 32; o > 0; o >>= 1) m = fmaxf(m, __shfl_down(m, o));
  __shared__ float red[4];
  if ((t & 63) == 0) red[t >> 6] = m;
  __syncthreads();
  float M4 = fmaxf(fmaxf(red[0], red[1]), fmaxf(red[2], red[3]));
  float v0 = __expf(e0 - M4), v1 = __expf(e1 - M4);
  float s = v0 + v1;
  for (int o = 32; o > 0; o >>= 1) s += __shfl_down(s, o);
  __syncthreads();
  if ((t & 63) == 0) red[t >> 6] = s;
  __syncthreads();
  float S4 = red[0] + red[1] + red[2] + red[3];
  float inv = qmask[row] / S4;
  attnb[row * Ss + t]       = __float2bfloat16(v0 * inv);
  attnb[row * Ss + t + 256] = __float2bfloat16(v1 * inv);
}

// ---------- GRU recurrence, weights register-resident as packed fp16 ----------
__global__ __launch_bounds__(512, 2) void gru_kernel(
    const bf16* __restrict__ xp,    // [2][88][S][3H] bf16 ws, includes bih
    const void* __restrict__ Whh,   // [2][3H][H] input dtype
    const void* __restrict__ bhh,   // [2][3H] input dtype
    float* __restrict__ hbuf,       // [2][88][H]
    const int* __restrict__ flags)
{
  int flag = flags[0];
  int idx = blockIdx.x;
  int dir = idx / 88, n = idx - dir * 88;
  int tid = threadIdx.x;
  int c = tid & 255;
  int q = tid >> 8;
  const unsigned short* xpb =
      (const unsigned short*)xp + ((long)(dir * 88 + n)) * Ss * Dd;

  unsigned w[3][64];
#pragma unroll
  for (int g = 0; g < 3; g++) {
    long rowBase = ((long)dir * Dd + g * 256 + c) * Hh + q * 128;
    if (flag) {
      const float4* s4 = (const float4*)((const float*)Whh + rowBase);
#pragma unroll
      for (int i = 0; i < 32; i++) {
        float4 v = s4[i];
        w[g][2 * i]     = packh2(v.x, v.y);
        w[g][2 * i + 1] = packh2(v.z, v.w);
      }
    } else {
      const uint4* s4 = (const uint4*)((const bf16*)Whh + rowBase);
#pragma unroll
      for (int i = 0; i < 16; i++) {
        uint4 v = s4[i];
        w[g][4 * i]     = packh2(blo(v.x), bhi(v.x));
        w[g][4 * i + 1] = packh2(blo(v.y), bhi(v.y));
        w[g][4 * i + 2] = packh2(blo(v.z), bhi(v.z));
        w[g][4 * i + 3] = packh2(blo(v.w), bhi(v.w));
      }
    }
  }

  __shared__ __align__(16) unsigned short hsh[256];
  __shared__ float partial[2][3][256];
  __shared__ unsigned short xsh[2][768];
  float bh[3] = {0.f, 0.f, 0.f};
  float hprev = 0.f;
  if (tid < 256) hsh[tid] = 0;
  if (q == 0) {
#pragma unroll
    for (int g = 0; g < 3; g++) bh[g] = ldg_any(bhh, dir * Dd + g * 256 + c, flag);
    int t0 = dir ? (Ss - 1) : 0;
#pragma unroll
    for (int g = 0; g < 3; g++) xsh[0][g * 256 + c] = xpb[(long)t0 * Dd + g * 256 + c];
  }
  __syncthreads();

  const uint4* hp = (const uint4*)(hsh + q * 128);
  for (int tt = 0; tt < Ss; tt++) {
    unsigned short xnr = 0, xnz = 0, xnn = 0;
    if (q == 0) {
      int ttn = (tt < Ss - 1) ? tt + 1 : tt;
      int tn = dir ? (Ss - 1 - ttn) : ttn;
      const unsigned short* xrow = xpb + (long)tn * Dd;
      xnr = xrow[c]; xnz = xrow[256 + c]; xnn = xrow[512 + c];
    }
    float ar = 0.f, az = 0.f, an = 0.f;
#pragma unroll
    for (int jj = 0; jj < 16; jj++) {
      uint4 hv = hp[jj];
      ar = dot2u(w[0][4 * jj],     hv.x, ar);
      ar = dot2u(w[0][4 * jj + 1], hv.y, ar);
      ar = dot2u(w[0][4 * jj + 2], hv.z, ar);
      ar = dot2u(w[0][4 * jj + 3], hv.w, ar);
      az = dot2u(w[1][4 * jj],     hv.x, az);
      az = dot2u(w[1][4 * jj + 1], hv.y, az);
      az = dot2u(w[1][4 * jj + 2], hv.z, az);
      az = dot2u(w[1][4 * jj + 3], hv.w, az);
      an = dot2u(w[2][4 * jj],     hv.x, an);
      an = dot2u(w[2][4 * jj + 1], hv.y, an);
      an = dot2u(w[2][4 * jj + 2], hv.z, an);
      an = dot2u(w[2][4 * jj + 3], hv.w, an);
    }
    partial[q][0][c] = ar;
    partial[q][1][c] = az;
    partial[q][2][c] = an;
    if (q == 0) {
      int nb = (tt + 1) & 1;
      xsh[nb][c] = xnr; xsh[nb][256 + c] = xnz; xsh[nb][512 + c] = xnn;
    }
    __syncthreads();
    if (q == 0) {
      int cb = tt & 1;
      float agr = partial[0][0][c] + partial[1][0][c] + bh[0];
      float agz = partial[0][1][c] + partial[1][1][c] + bh[1];
      float agn = partial[0][2][c] + partial[1][2][c] + bh[2];
      float xr = b2f(xsh[cb][c]);
      float xz = b2f(xsh[cb][256 + c]);
      float xn = b2f(xsh[cb][512 + c]);
      float r = 1.f / (1.f + __expf(-(xr + agr)));
      float z = 1.f / (1.f + __expf(-(xz + agz)));
      float nn2 = tanhf(xn + r * agn);
      float hnew = (1.f - z) * nn2 + z * hprev;
      hprev = hnew;
      __half hh = __float2half(hnew);
      hsh[c] = __builtin_bit_cast(unsigned short, hh);
    }
    __syncthreads();
  }
  if (q == 0) hbuf[((long)(dir * 88 + n)) * Hh + c] = hprev;
}

// ---------- final head ----------
__global__ __launch_bounds__(256) void head_kernel(
    const float* __restrict__ hbuf, const void* __restrict__ W1,
    const void* __restrict__ b1, void* __restrict__ out,
    const int* __restrict__ flags)
{
  int flag = flags[0];
  int n = blockIdx.x;
  int c = threadIdx.x;
  float v = hbuf[(long)n * Hh + c] * ldg_any(W1, c, flag)
          + hbuf[(long)(88 + n) * Hh + c] * ldg_any(W1, 256 + c, flag);
  for (int o = 32; o > 0; o >>= 1) v += __shfl_down(v, o);
  __shared__ float red[4];
  if ((c & 63) == 0) red[c >> 6] = v;
  __syncthreads();
  if (c == 0) {
    float s = red[0] + red[1] + red[2] + red[3] + ldg_any(b1, 0, flag);
    float sig = 1.f / (1.f + __expf(-s));
    int k = n / Bb, b = n - k * Bb;
    int o = b * NATT + k;
    if (flag) ((float*)out)[o] = sig;
    else      stf((bf16*)out + o, sig);
  }
}

extern "C" void kernel_launch(void* const* d_in, const int* in_sizes, int n_in,
                              void* d_out, int out_size, void* d_ws, size_t ws_size,
                              hipStream_t stream) {
  const void* labels = d_in[0];
  const void* seq  = d_in[1];
  const void* emb  = d_in[2];
  const void* Wq   = d_in[3];
  const void* bq   = d_in[4];
  const void* Wk   = d_in[5];
  const void* bk   = d_in[6];
  const void* Wv   = d_in[7];
  const void* bv   = d_in[8];
  const void* Wih  = d_in[9];
  const void* Whh  = d_in[10];
  const void* bih  = d_in[11];
  const void* bhh  = d_in[12];
  const void* W1   = d_in[13];
  const void* b1   = d_in[14];

  char* p = (char*)d_ws;
  size_t off = 0;
  auto alloc = [&](size_t bytes) -> void* {
    void* r = p + off; off += (bytes + 255) & ~(size_t)255; return r;
  };
  int*   flags = (int*)alloc(2 * sizeof(int));
  bf16*  amb   = (bf16*)alloc(4096UL * 768 * 2);
  bf16*  seqb  = (bf16*)alloc(4096UL * 768 * 2);
  float* qmask = (float*)alloc(4096UL * 4);
  bf16*  WqT   = (bf16*)alloc(768UL * 768 * 2);
  bf16*  WkT   = (bf16*)alloc(768UL * 768 * 2);
  bf16*  WvT   = (bf16*)alloc(768UL * 768 * 2);
  bf16*  WihB  = (bf16*)alloc(2UL * 768 * 768 * 2);
  bf16*  Qb    = (bf16*)alloc(4096UL * 768 * 2);
  bf16*  Kb    = (bf16*)alloc(4096UL * 768 * 2);
  bf16*  Vt    = (bf16*)alloc(768UL * 4096 * 2);   // [e][b*512+m]
  float* sc    = (float*)alloc(8UL * 512 * 512 * 4);
  bf16*  attnb = (bf16*)alloc(8UL * 512 * 512 * 2);
  bf16*  elout = (bf16*)alloc(4096UL * 768 * 2);
  bf16*  xpb   = (bf16*)alloc(2UL * 88 * 512 * 768 * 2);
  float* hbuf  = (float*)alloc(2UL * 88 * 256 * 4);
  if (off > ws_size) return;

  probe_kernel<<<1, 64, 0, stream>>>((const unsigned short*)seq,
                                     (const unsigned*)labels, flags);
  build_am_kernel<<<4096, 256, 0, stream>>>(labels, emb, seq, amb, seqb, qmask, flags);
  convert_kernel<<<(2 * 768 * 768 + 255) / 256, 256, 0, stream>>>(
      Wih, WihB, 2L * 768 * 768, flags);

  const float scl = 1.f / sqrtf(768.f);
  for (int k = 0; k < NATT; k++) {
    long wo = (long)k * 768 * 768;
    long bo = (long)k * 768;
    transpose3_kernel<<<dim3(24, 24, 3), 256, 0, stream>>>(
        Wq, Wk, Wv, wo, WqT, WkT, WvT, flags);
    // Q = relu(amb @ WqT^T + bq)
    gemm_mfma<<<dim3(6, 32, 1), 256, 0, stream>>>(
        amb, 768, 0, WqT, 768, 0, bq, bo, Qb, 768, 0, 0,
        nullptr, nullptr, 4096, 768, 768, 1.f, 1, flags);
    gemm_mfma<<<dim3(6, 32, 1), 256, 0, stream>>>(
        seqb, 768, 0, WkT, 768, 0, bk, bo, Kb, 768, 0, 0,
        nullptr, nullptr, 4096, 768, 768, 1.f, 1, flags);
    // V, stored transposed: Vt[e][b*512+m]
    gemm_mfma<<<dim3(6, 32, 1), 256, 0, stream>>>(
        seqb, 768, 0, WvT, 768, 0, bv, bo, Vt, 4096, 0, 1,
        nullptr, nullptr, 4096, 768, 768, 1.f, 1, flags);
    // scores = Q @ K^T / sqrt(D), batched over b, fp32 out
    gemm_mfma<<<dim3(4, 4, 8), 256, 0, stream>>>(
        Qb, 768, 512L * 768, Kb, 768, 512L * 768, nullptr, 0,
        sc, 512, 512L * 512, 2, nullptr, nullptr, 512, 512, 768, scl, 0, flags);
    softmax_mask_kernel<<<4096, 256, 0, stream>>>(sc, qmask, attnb);
    // elout = attn @ V + am + seq (batched over b)
    gemm_mfma<<<dim3(6, 4, 8), 256, 0, stream>>>(
        attnb, 512, 512L * 512, Vt, 4096, 512, nullptr, 0,
        elout, 768, 512L * 768, 0, amb, seqb, 512, 768, 512, 1.f, 0, flags);
    // xp[dir] for this k: elout @ Wih^T + bih -> bf16
    for (int d2 = 0; d2 < 2; d2++) {
      gemm_mfma<<<dim3(6, 32, 1), 256, 0, stream>>>(
          elout, 768, 0, WihB + (long)d2 * 768 * 768, 768, 0, bih, (long)d2 * 768,
          xpb + ((long)d2 * 88 + (long)k * 8) * 512 * 768, 768, 0, 0,
          nullptr, nullptr, 4096, 768, 768, 1.f, 0, flags);
    }
  }
  gru_kernel<<<176, 512, 0, stream>>>(xpb, Whh, bhh, hbuf, flags);
  head_kernel<<<88, 256, 0, stream>>>(hbuf, W1, b1, d_out, flags);
}

// Round 5
// 1637.313 us; speedup vs baseline: 15.7733x; 1.9025x over previous
//
#include <hip/hip_runtime.h>
#include <hip/hip_bf16.h>
#include <hip/hip_fp16.h>
#include <math.h>

typedef __hip_bfloat16 bf16;
typedef __attribute__((ext_vector_type(8))) short short8;
typedef __attribute__((ext_vector_type(4))) float f32x4;

#define NATT 11
#define Bb 8
#define Ss 512
#define Dd 768
#define Hh 256
#define WSLICE 589824L  // 768*768

__device__ __forceinline__ void stf(float* p, float v) { *p = v; }
__device__ __forceinline__ void stf(bf16* p, float v) { *p = __float2bfloat16(v); }

__device__ __forceinline__ float blo(unsigned u) { return __uint_as_float(u << 16); }
__device__ __forceinline__ float bhi(unsigned u) { return __uint_as_float(u & 0xffff0000u); }
__device__ __forceinline__ float b2f(unsigned short u) { return __uint_as_float(((unsigned)u) << 16); }

__device__ __forceinline__ float ldg_any(const void* base, long idx, int flag) {
  if (flag) return ((const float*)base)[idx];
  return __bfloat162float(((const bf16*)base)[idx]);
}

__device__ __forceinline__ unsigned packh2(float a, float b) {
  __half2 hh = __floats2half2_rn(a, b);
  return __builtin_bit_cast(unsigned, hh);
}

typedef _Float16 f16x2 __attribute__((ext_vector_type(2)));

__device__ __forceinline__ float dot2u(unsigned a, unsigned b, float c) {
#if __has_builtin(__builtin_amdgcn_fdot2)
  return __builtin_amdgcn_fdot2(__builtin_bit_cast(f16x2, a),
                                __builtin_bit_cast(f16x2, b), c, false);
#else
  __half2 ah = __builtin_bit_cast(__half2, a);
  __half2 bh = __builtin_bit_cast(__half2, b);
  float2 af = __half22float2(ah), bf = __half22float2(bh);
  return c + af.x * bf.x + af.y * bf.y;
#endif
}

// async global->LDS, 16B per lane, dest = ldsbase + lane*16
__device__ __forceinline__ void load_lds16(const void* g, void* l) {
  __builtin_amdgcn_global_load_lds(
      (const __attribute__((address_space(1))) unsigned int*)g,
      (__attribute__((address_space(3))) unsigned int*)l, 16, 0, 0);
}

// ---------- dtype probe ----------
__global__ __launch_bounds__(64) void probe_kernel(
    const unsigned short* __restrict__ sequ, const unsigned* __restrict__ labu,
    int* __restrict__ flags)
{
  int t = threadIdx.x;
  int wild = 0;
#pragma unroll
  for (int i = 0; i < 4; i++) {
    unsigned short v = sequ[t + i * 64];
    int e = (v >> 7) & 0xFF;
    if (e < 90 || e > 160) wild++;
  }
  int nzodd = 0;
#pragma unroll
  for (int i = 0; i < 2; i++) {
    unsigned w = labu[(t + i * 64) * 2 + 1];
    if (w != 0) nzodd++;
  }
  for (int o = 32; o > 0; o >>= 1) {
    wild  += __shfl_down(wild, o);
    nzodd += __shfl_down(nzodd, o);
  }
  if (t == 0) {
    flags[0] = (wild > 32) ? 1 : 0;
    flags[1] = (nzodd == 0) ? 1 : 0;
  }
}

// ---------- build am/seq bf16 + qmask ----------
__global__ __launch_bounds__(256) void build_am_kernel(
    const void* __restrict__ labels, const void* __restrict__ emb,
    const void* __restrict__ seq, bf16* __restrict__ amb,
    bf16* __restrict__ seqb, float* __restrict__ qmask,
    const int* __restrict__ flags)
{
  int fflag = flags[0], lflag = flags[1];
  int row = blockIdx.x;
  long lab = lflag ? (long)((const long long*)labels)[row]
                   : (long)((const int*)labels)[row];
  int t = threadIdx.x;
  float s = 0.f;
#pragma unroll
  for (int i = 0; i < 3; i++) {
    int e = t + i * 256;
    float v = ldg_any(emb, lab * Dd + e, fflag);
    amb[(long)row * Dd + e] = __float2bfloat16(v);
    s += v;
    seqb[(long)row * Dd + e] = __float2bfloat16(ldg_any(seq, (long)row * Dd + e, fflag));
  }
  for (int o = 32; o > 0; o >>= 1) s += __shfl_down(s, o);
  __shared__ float red[4];
  if ((t & 63) == 0) red[t >> 6] = s;
  __syncthreads();
  if (t == 0) {
    float tot = red[0] + red[1] + red[2] + red[3];
    qmask[row] = (tot != 0.f) ? 1.f : 0.f;
  }
}

// ---------- transpose group of Wq/Wk/Wv branch slices to [N][K] bf16 ----------
__global__ __launch_bounds__(256) void transpose3_kernel(
    const void* __restrict__ Wq, const void* __restrict__ Wk,
    const void* __restrict__ Wv, int k0,
    bf16* __restrict__ WT, const int* __restrict__ flags)
{
  int flag = flags[0];
  __shared__ float tile[32][33];
  int z = blockIdx.z;
  int m = z / 3, wsel = z - m * 3;
  const void* src = (wsel == 0) ? Wq : (wsel == 1) ? Wk : Wv;
  long off = (long)(k0 + m) * WSLICE;
  bf16* dst = WT + (long)z * WSLICE;
  int kk0 = blockIdx.y * 32, n0 = blockIdx.x * 32;
  int tx = threadIdx.x & 31, ty = threadIdx.x >> 5;
#pragma unroll
  for (int i = 0; i < 4; i++)
    tile[ty + i * 8][tx] = ldg_any(src, off + (long)(kk0 + ty + i * 8) * Dd + n0 + tx, flag);
  __syncthreads();
#pragma unroll
  for (int i = 0; i < 4; i++)
    dst[(long)(n0 + ty + i * 8) * Dd + kk0 + tx] = __float2bfloat16(tile[tx][ty + i * 8]);
}

// ---------- convert Wih to bf16 ----------
__global__ __launch_bounds__(256) void convert_kernel(
    const void* __restrict__ src, bf16* __restrict__ dst, long n,
    const int* __restrict__ flags)
{
  int flag = flags[0];
  long i = (long)blockIdx.x * 256 + threadIdx.x;
  if (i < n) dst[i] = __float2bfloat16(ldg_any(src, i, flag));
}

// ---------- MFMA GEMM core (m97-style): C = epi(scale*A@B^T) ----------
// A[M,K], B[N,K] bf16 K-contiguous. LDS tiles 128x32 unpadded, staged with
// global_load_lds width-16. cMode: 0=bf16, 1=bf16 transposed, 2=fp32.
__device__ __forceinline__ void gemm_mfma_core(
    const bf16* __restrict__ Ab, long ldA,
    const bf16* __restrict__ Bbp, long ldB,
    bf16* As, bf16* Bs, int bm, int bn, int K,
    const void* bias, long bOff,
    void* C, long ldC, long cBase, int cMode,
    const bf16* res1, const bf16* res2,
    float scale, int relu, int fflag)
{
  int tid = threadIdx.x;
  int lane = tid & 63, w = tid >> 6;
  int mo = (w & 1) * 64, no = (w >> 1) * 64;
  int l15 = lane & 15, q4 = lane >> 4;
  int gr = lane >> 2;          // row within 16-row group
  int gs = (lane & 3) * 8;     // bf16 col start (16B)
  const bf16* aS0 = Ab + (long)(bm + w * 16 + gr) * ldA + gs;
  const bf16* aS1 = aS0 + 64 * ldA;
  const bf16* bS0 = Bbp + (long)(bn + w * 16 + gr) * ldB + gs;
  const bf16* bS1 = bS0 + 64 * ldB;
  bf16* aD0 = As + w * 512;          // rows [w*16, w*16+16)
  bf16* aD1 = As + 2048 + w * 512;   // rows [64+w*16, ...)
  bf16* bD0 = Bs + w * 512;
  bf16* bD1 = Bs + 2048 + w * 512;

  f32x4 acc[4][4];
#pragma unroll
  for (int i = 0; i < 4; i++)
#pragma unroll
    for (int j = 0; j < 4; j++)
#pragma unroll
      for (int r = 0; r < 4; r++) acc[i][j][r] = 0.f;

  for (int k0 = 0; k0 < K; k0 += 32) {
    load_lds16(aS0, aD0);
    load_lds16(aS1, aD1);
    load_lds16(bS0, bD0);
    load_lds16(bS1, bD1);
    aS0 += 32; aS1 += 32; bS0 += 32; bS1 += 32;
    __syncthreads();   // vmcnt(0) drain + barrier
    short8 af[4], bfv[4];
#pragma unroll
    for (int i = 0; i < 4; i++)
      af[i] = *(const short8*)(As + (mo + i * 16 + l15) * 32 + q4 * 8);
#pragma unroll
    for (int j = 0; j < 4; j++)
      bfv[j] = *(const short8*)(Bs + (no + j * 16 + l15) * 32 + q4 * 8);
#pragma unroll
    for (int i = 0; i < 4; i++)
#pragma unroll
      for (int j = 0; j < 4; j++)
        acc[i][j] = __builtin_amdgcn_mfma_f32_16x16x32_bf16(af[i], bfv[j], acc[i][j], 0, 0, 0);
    __syncthreads();
  }

  float bsv[4];
#pragma unroll
  for (int j = 0; j < 4; j++) {
    int colg = bn + no + j * 16 + l15;
    bsv[j] = bias ? ldg_any(bias, bOff + colg, fflag) : 0.f;
  }
#pragma unroll
  for (int i = 0; i < 4; i++) {
#pragma unroll
    for (int j = 0; j < 4; j++) {
      int colg = bn + no + j * 16 + l15;
      if (cMode == 1) {
        int rowg0 = bm + mo + i * 16 + q4 * 4;
        ushort4 pk;
        unsigned short tmp[4];
#pragma unroll
        for (int r = 0; r < 4; r++) {
          float v = acc[i][j][r] * scale + bsv[j];
          if (relu) v = fmaxf(v, 0.f);
          tmp[r] = __builtin_bit_cast(unsigned short, __float2bfloat16(v));
        }
        pk.x = tmp[0]; pk.y = tmp[1]; pk.z = tmp[2]; pk.w = tmp[3];
        *(ushort4*)((bf16*)C + cBase + (long)colg * ldC + rowg0) = pk;
      } else {
#pragma unroll
        for (int r = 0; r < 4; r++) {
          int rowg = bm + mo + i * 16 + q4 * 4 + r;
          float v = acc[i][j][r] * scale + bsv[j];
          if (relu) v = fmaxf(v, 0.f);
          long off2 = cBase + (long)rowg * ldC + colg;
          if (res1) v += __bfloat162float(res1[off2 - cBase]);
          if (res2) v += __bfloat162float(res2[off2 - cBase]);
          if (cMode == 2) ((float*)C)[off2] = v;
          else            ((bf16*)C)[off2] = __float2bfloat16(v);
        }
      }
    }
  }
}

// ---------- wrappers ----------
// z = m*3 + {0:Q,1:K,2:V}
__global__ __launch_bounds__(256, 2) void proj_kernel(
    const bf16* __restrict__ amb, const bf16* __restrict__ seqb,
    const bf16* __restrict__ WT,
    const void* __restrict__ bq, const void* __restrict__ bk,
    const void* __restrict__ bv, int k0,
    bf16* __restrict__ Qb, bf16* __restrict__ Kb, bf16* __restrict__ Vt,
    const int* __restrict__ flags)
{
  __shared__ __align__(16) bf16 As[4096];
  __shared__ __align__(16) bf16 Bs[4096];
  int z = blockIdx.z;
  int m = z / 3, wsel = z - m * 3;
  const bf16* A = (wsel == 0) ? amb : seqb;
  const bf16* B = WT + (long)z * WSLICE;
  const void* bias = (wsel == 0) ? bq : (wsel == 1) ? bk : bv;
  long bOff = (long)(k0 + m) * Dd;
  void* C; long ldC; int cMode;
  if (wsel == 2) { C = Vt + (long)m * Dd * 4096; ldC = 4096; cMode = 1; }
  else { C = ((wsel == 0) ? Qb : Kb) + (long)m * 4096 * Dd; ldC = Dd; cMode = 0; }
  gemm_mfma_core(A, Dd, B, Dd, As, Bs, blockIdx.y * 128, blockIdx.x * 128, Dd,
                 bias, bOff, C, ldC, 0, cMode, nullptr, nullptr, 1.f, 1, flags[0]);
}

// z = m*8 + b
__global__ __launch_bounds__(256, 2) void qk_kernel(
    const bf16* __restrict__ Qb, const bf16* __restrict__ Kb,
    bf16* __restrict__ sc, float scl, const int* __restrict__ flags)
{
  __shared__ __align__(16) bf16 As[4096];
  __shared__ __align__(16) bf16 Bs[4096];
  int z = blockIdx.z;
  int m = z >> 3, b = z & 7;
  const bf16* A = Qb + ((long)m * 4096 + b * 512) * Dd;
  const bf16* B = Kb + ((long)m * 4096 + b * 512) * Dd;
  bf16* C = sc + (long)z * 512 * 512;
  gemm_mfma_core(A, Dd, B, Dd, As, Bs, blockIdx.y * 128, blockIdx.x * 128, Dd,
                 nullptr, 0, C, 512, 0, 0, nullptr, nullptr, scl, 0, flags[0]);
}

// z = m*8 + b
__global__ __launch_bounds__(256, 2) void av_kernel(
    const bf16* __restrict__ sc, const bf16* __restrict__ Vt,
    const bf16* __restrict__ amb, const bf16* __restrict__ seqb,
    bf16* __restrict__ elout, const int* __restrict__ flags)
{
  __shared__ __align__(16) bf16 As[4096];
  __shared__ __align__(16) bf16 Bs[4096];
  int z = blockIdx.z;
  int m = z >> 3, b = z & 7;
  const bf16* A = sc + (long)z * 512 * 512;
  const bf16* B = Vt + (long)m * Dd * 4096 + b * 512;
  const bf16* r1 = amb + (long)b * 512 * Dd;
  const bf16* r2 = seqb + (long)b * 512 * Dd;
  bf16* C = elout + ((long)m * 4096 + b * 512) * Dd;
  gemm_mfma_core(A, 512, B, 4096, As, Bs, blockIdx.y * 128, blockIdx.x * 128, 512,
                 nullptr, 0, C, Dd, 0, 0, r1, r2, 1.f, 0, flags[0]);
}

// z = m*2 + dir
__global__ __launch_bounds__(256, 2) void xp_kernel(
    const bf16* __restrict__ elout, const bf16* __restrict__ WihB,
    const void* __restrict__ bih, int k0,
    bf16* __restrict__ xpb, const int* __restrict__ flags)
{
  __shared__ __align__(16) bf16 As[4096];
  __shared__ __align__(16) bf16 Bs[4096];
  int z = blockIdx.z;
  int m = z >> 1, dir = z & 1;
  const bf16* A = elout + (long)m * 4096 * Dd;
  const bf16* B = WihB + (long)dir * WSLICE;
  bf16* C = xpb + ((long)(dir * 88 + (k0 + m) * 8)) * 512 * Dd;
  gemm_mfma_core(A, Dd, B, Dd, As, Bs, blockIdx.y * 128, blockIdx.x * 128, Dd,
                 bih, (long)dir * Dd, C, Dd, 0, 0, nullptr, nullptr, 1.f, 0, flags[0]);
}

// ---------- softmax in place (bf16) + query mask ----------
__global__ __launch_bounds__(256) void softmax_mask_kernel(
    bf16* __restrict__ sc, const float* __restrict__ qmask)
{
  long row = blockIdx.x;
  bf16* p = sc + row * Ss;
  int t = threadIdx.x;
  float e0 = __bfloat162float(p[t]), e1 = __bfloat162float(p[t + 256]);
  float m = fmaxf(e0, e1);
  for (int o = 32; o > 0; o >>= 1) m = fmaxf(m, __shfl_down(m, o));
  __shared__ float red[4];
  if ((t & 63) == 0) red[t >> 6] = m;
  __syncthreads();
  float M4 = fmaxf(fmaxf(red[0], red[1]), fmaxf(red[2], red[3]));
  float v0 = __expf(e0 - M4), v1 = __expf(e1 - M4);
  float s = v0 + v1;
  for (int o = 32; o > 0; o >>= 1) s += __shfl_down(s, o);
  __syncthreads();
  if ((t & 63) == 0) red[t >> 6] = s;
  __syncthreads();
  float S4 = red[0] + red[1] + red[2] + red[3];
  float inv = qmask[row & 4095] / S4;
  p[t]       = __float2bfloat16(v0 * inv);
  p[t + 256] = __float2bfloat16(v1 * inv);
}

// ---------- GRU recurrence ----------
__global__ __launch_bounds__(512, 2) void gru_kernel(
    const bf16* __restrict__ xp, const void* __restrict__ Whh,
    const void* __restrict__ bhh, float* __restrict__ hbuf,
    const int* __restrict__ flags)
{
  int flag = flags[0];
  int idx = blockIdx.x;
  int dir = idx / 88, n = idx - dir * 88;
  int tid = threadIdx.x;
  int c = tid & 255;
  int q = tid >> 8;
  const unsigned short* xpb =
      (const unsigned short*)xp + ((long)(dir * 88 + n)) * Ss * Dd;

  unsigned w[3][64];
#pragma unroll
  for (int g = 0; g < 3; g++) {
    long rowBase = ((long)dir * Dd + g * 256 + c) * Hh + q * 128;
    if (flag) {
      const float4* s4 = (const float4*)((const float*)Whh + rowBase);
#pragma unroll
      for (int i = 0; i < 32; i++) {
        float4 v = s4[i];
        w[g][2 * i]     = packh2(v.x, v.y);
        w[g][2 * i + 1] = packh2(v.z, v.w);
      }
    } else {
      const uint4* s4 = (const uint4*)((const bf16*)Whh + rowBase);
#pragma unroll
      for (int i = 0; i < 16; i++) {
        uint4 v = s4[i];
        w[g][4 * i]     = packh2(blo(v.x), bhi(v.x));
        w[g][4 * i + 1] = packh2(blo(v.y), bhi(v.y));
        w[g][4 * i + 2] = packh2(blo(v.z), bhi(v.z));
        w[g][4 * i + 3] = packh2(blo(v.w), bhi(v.w));
      }
    }
  }

  __shared__ __align__(16) unsigned short hsh[256];
  __shared__ float partial[2][3][256];
  __shared__ unsigned short xsh[2][768];
  float bh[3] = {0.f, 0.f, 0.f};
  float hprev = 0.f;
  unsigned short x1r = 0, x1z = 0, x1n = 0;
  if (tid < 256) hsh[tid] = 0;
  if (q == 0) {
#pragma unroll
    for (int g = 0; g < 3; g++) bh[g] = ldg_any(bhh, dir * Dd + g * 256 + c, flag);
    int t0 = dir ? (Ss - 1) : 0;
    int t1 = dir ? (Ss - 2) : 1;
#pragma unroll
    for (int g = 0; g < 3; g++) xsh[0][g * 256 + c] = xpb[(long)t0 * Dd + g * 256 + c];
    const unsigned short* x1row = xpb + (long)t1 * Dd;
    x1r = x1row[c]; x1z = x1row[256 + c]; x1n = x1row[512 + c];
  }
  __syncthreads();

  const uint4* hp = (const uint4*)(hsh + q * 128);
  for (int tt = 0; tt < Ss; tt++) {
    // prefetch x for step tt+2 (2-deep pipeline vs HBM latency)
    unsigned short x2r = 0, x2z = 0, x2n = 0;
    if (q == 0) {
      int tt2 = (tt + 2 < Ss) ? tt + 2 : Ss - 1;
      int t2 = dir ? (Ss - 1 - tt2) : tt2;
      const unsigned short* xrow = xpb + (long)t2 * Dd;
      x2r = xrow[c]; x2z = xrow[256 + c]; x2n = xrow[512 + c];
    }
    float ar = 0.f, az = 0.f, an = 0.f;
#pragma unroll
    for (int jj = 0; jj < 16; jj++) {
      uint4 hv = hp[jj];
      ar = dot2u(w[0][4 * jj],     hv.x, ar);
      ar = dot2u(w[0][4 * jj + 1], hv.y, ar);
      ar = dot2u(w[0][4 * jj + 2], hv.z, ar);
      ar = dot2u(w[0][4 * jj + 3], hv.w, ar);
      az = dot2u(w[1][4 * jj],     hv.x, az);
      az = dot2u(w[1][4 * jj + 1], hv.y, az);
      az = dot2u(w[1][4 * jj + 2], hv.z, az);
      az = dot2u(w[1][4 * jj + 3], hv.w, az);
      an = dot2u(w[2][4 * jj],     hv.x, an);
      an = dot2u(w[2][4 * jj + 1], hv.y, an);
      an = dot2u(w[2][4 * jj + 2], hv.z, an);
      an = dot2u(w[2][4 * jj + 3], hv.w, an);
    }
    partial[q][0][c] = ar;
    partial[q][1][c] = az;
    partial[q][2][c] = an;
    if (q == 0) {
      int nb = (tt + 1) & 1;
      xsh[nb][c] = x1r; xsh[nb][256 + c] = x1z; xsh[nb][512 + c] = x1n;
    }
    __syncthreads();
    if (q == 0) {
      int cb = tt & 1;
      float agr = partial[0][0][c] + partial[1][0][c] + bh[0];
      float agz = partial[0][1][c] + partial[1][1][c] + bh[1];
      float agn = partial[0][2][c] + partial[1][2][c] + bh[2];
      float xr = b2f(xsh[cb][c]);
      float xz = b2f(xsh[cb][256 + c]);
      float xn = b2f(xsh[cb][512 + c]);
      float r = 1.f / (1.f + __expf(-(xr + agr)));
      float z = 1.f / (1.f + __expf(-(xz + agz)));
      float targ = xn + r * agn;
      float e2 = __expf(2.f * targ);
      float nn2 = 1.f - 2.f / (e2 + 1.f);   // tanh, overflow-safe
      float hnew = (1.f - z) * nn2 + z * hprev;
      hprev = hnew;
      __half hh = __float2half(hnew);
      hsh[c] = __builtin_bit_cast(unsigned short, hh);
      x1r = x2r; x1z = x2z; x1n = x2n;
    }
    __syncthreads();
  }
  if (q == 0) hbuf[((long)(dir * 88 + n)) * Hh + c] = hprev;
}

// ---------- final head ----------
__global__ __launch_bounds__(256) void head_kernel(
    const float* __restrict__ hbuf, const void* __restrict__ W1,
    const void* __restrict__ b1, void* __restrict__ out,
    const int* __restrict__ flags)
{
  int flag = flags[0];
  int n = blockIdx.x;
  int c = threadIdx.x;
  float v = hbuf[(long)n * Hh + c] * ldg_any(W1, c, flag)
          + hbuf[(long)(88 + n) * Hh + c] * ldg_any(W1, 256 + c, flag);
  for (int o = 32; o > 0; o >>= 1) v += __shfl_down(v, o);
  __shared__ float red[4];
  if ((c & 63) == 0) red[c >> 6] = v;
  __syncthreads();
  if (c == 0) {
    float s = red[0] + red[1] + red[2] + red[3] + ldg_any(b1, 0, flag);
    float sig = 1.f / (1.f + __expf(-s));
    int k = n / Bb, b = n - k * Bb;
    int o = b * NATT + k;
    if (flag) ((float*)out)[o] = sig;
    else      stf((bf16*)out + o, sig);
  }
}

extern "C" void kernel_launch(void* const* d_in, const int* in_sizes, int n_in,
                              void* d_out, int out_size, void* d_ws, size_t ws_size,
                              hipStream_t stream) {
  const void* labels = d_in[0];
  const void* seq  = d_in[1];
  const void* emb  = d_in[2];
  const void* Wq   = d_in[3];
  const void* bq   = d_in[4];
  const void* Wk   = d_in[5];
  const void* bk   = d_in[6];
  const void* Wv   = d_in[7];
  const void* bv   = d_in[8];
  const void* Wih  = d_in[9];
  const void* Whh  = d_in[10];
  const void* bih  = d_in[11];
  const void* bhh  = d_in[12];
  const void* W1   = d_in[13];
  const void* b1   = d_in[14];

  char* p = (char*)d_ws;
  size_t off = 0;
  auto alloc = [&](size_t bytes) -> void* {
    void* r = p + off; off += (bytes + 255) & ~(size_t)255; return r;
  };
  int*   flags = (int*)alloc(2 * sizeof(int));
  bf16*  amb   = (bf16*)alloc(4096UL * 768 * 2);
  bf16*  seqb  = (bf16*)alloc(4096UL * 768 * 2);
  float* qmask = (float*)alloc(4096UL * 4);
  bf16*  WihB  = (bf16*)alloc(2UL * WSLICE * 2);
  bf16*  WT    = (bf16*)alloc(6UL * WSLICE * 2);       // [G=2][3][768][768]
  bf16*  Qb    = (bf16*)alloc(2UL * 4096 * 768 * 2);   // also elout (aliased)
  bf16*  Kb    = (bf16*)alloc(2UL * 4096 * 768 * 2);
  bf16*  Vt    = (bf16*)alloc(2UL * 768 * 4096 * 2);
  bf16*  sc    = (bf16*)alloc(2UL * 8 * 512 * 512 * 2);
  bf16*  xpb   = (bf16*)alloc(2UL * 88 * 512 * 768 * 2);
  float* hbuf  = (float*)alloc(2UL * 88 * 256 * 4);
  bf16*  elout = Qb;   // Qb dead after qk_kernel; reuse for elout
  if (off > ws_size) return;

  probe_kernel<<<1, 64, 0, stream>>>((const unsigned short*)seq,
                                     (const unsigned*)labels, flags);
  build_am_kernel<<<4096, 256, 0, stream>>>(labels, emb, seq, amb, seqb, qmask, flags);
  convert_kernel<<<(2 * 768 * 768 + 255) / 256, 256, 0, stream>>>(
      Wih, WihB, 2L * WSLICE, flags);

  const float scl = 1.f / sqrtf(768.f);
  for (int g0 = 0; g0 < NATT; g0 += 2) {
    int G = (NATT - g0 >= 2) ? 2 : 1;
    transpose3_kernel<<<dim3(24, 24, 3 * G), 256, 0, stream>>>(
        Wq, Wk, Wv, g0, WT, flags);
    proj_kernel<<<dim3(6, 32, 3 * G), 256, 0, stream>>>(
        amb, seqb, WT, bq, bk, bv, g0, Qb, Kb, Vt, flags);
    qk_kernel<<<dim3(4, 4, 8 * G), 256, 0, stream>>>(Qb, Kb, sc, scl, flags);
    softmax_mask_kernel<<<4096 * G, 256, 0, stream>>>(sc, qmask);
    av_kernel<<<dim3(6, 4, 8 * G), 256, 0, stream>>>(sc, Vt, amb, seqb, elout, flags);
    xp_kernel<<<dim3(6, 32, 2 * G), 256, 0, stream>>>(elout, WihB, bih, g0, xpb, flags);
  }
  gru_kernel<<<176, 512, 0, stream>>>(xpb, Whh, bhh, hbuf, flags);
  head_kernel<<<88, 256, 0, stream>>>(hbuf, W1, b1, d_out, flags);
}

// Round 6
// 1207.138 us; speedup vs baseline: 21.3943x; 1.3564x over previous
//
#include <hip/hip_runtime.h>
#include <hip/hip_bf16.h>
#include <hip/hip_fp16.h>
#include <math.h>

typedef __hip_bfloat16 bf16;
typedef __attribute__((ext_vector_type(8))) short short8;
typedef __attribute__((ext_vector_type(4))) float f32x4;

#define NATT 11
#define Bb 8
#define Ss 512
#define Dd 768
#define Hh 256
#define WSLICE 589824L  // 768*768

__device__ __forceinline__ void stf(float* p, float v) { *p = v; }
__device__ __forceinline__ void stf(bf16* p, float v) { *p = __float2bfloat16(v); }

__device__ __forceinline__ float blo(unsigned u) { return __uint_as_float(u << 16); }
__device__ __forceinline__ float bhi(unsigned u) { return __uint_as_float(u & 0xffff0000u); }
__device__ __forceinline__ float b2f(unsigned short u) { return __uint_as_float(((unsigned)u) << 16); }

__device__ __forceinline__ float ldg_any(const void* base, long idx, int flag) {
  if (flag) return ((const float*)base)[idx];
  return __bfloat162float(((const bf16*)base)[idx]);
}

__device__ __forceinline__ unsigned packh2(float a, float b) {
  __half2 hh = __floats2half2_rn(a, b);
  return __builtin_bit_cast(unsigned, hh);
}
__device__ __forceinline__ unsigned short f2h(float v) {
  __half h = __float2half(v);
  return __builtin_bit_cast(unsigned short, h);
}

typedef _Float16 f16x2 __attribute__((ext_vector_type(2)));

__device__ __forceinline__ float dot2u(unsigned a, unsigned b, float c) {
#if __has_builtin(__builtin_amdgcn_fdot2)
  return __builtin_amdgcn_fdot2(__builtin_bit_cast(f16x2, a),
                                __builtin_bit_cast(f16x2, b), c, false);
#else
  __half2 ah = __builtin_bit_cast(__half2, a);
  __half2 bh = __builtin_bit_cast(__half2, b);
  float2 af = __half22float2(ah), bf = __half22float2(bh);
  return c + af.x * bf.x + af.y * bf.y;
#endif
}

__device__ __forceinline__ void load_lds16(const void* g, void* l) {
  __builtin_amdgcn_global_load_lds(
      (const __attribute__((address_space(1))) unsigned int*)g,
      (__attribute__((address_space(3))) unsigned int*)l, 16, 0, 0);
}

// ---------- dtype probe ----------
__global__ __launch_bounds__(64) void probe_kernel(
    const unsigned short* __restrict__ sequ, const unsigned* __restrict__ labu,
    int* __restrict__ flags)
{
  int t = threadIdx.x;
  int wild = 0;
#pragma unroll
  for (int i = 0; i < 4; i++) {
    unsigned short v = sequ[t + i * 64];
    int e = (v >> 7) & 0xFF;
    if (e < 90 || e > 160) wild++;
  }
  int nzodd = 0;
#pragma unroll
  for (int i = 0; i < 2; i++) {
    unsigned w = labu[(t + i * 64) * 2 + 1];
    if (w != 0) nzodd++;
  }
  for (int o = 32; o > 0; o >>= 1) {
    wild  += __shfl_down(wild, o);
    nzodd += __shfl_down(nzodd, o);
  }
  if (t == 0) {
    flags[0] = (wild > 32) ? 1 : 0;
    flags[1] = (nzodd == 0) ? 1 : 0;
  }
}

// ---------- seq -> bf16 ----------
__global__ __launch_bounds__(256) void conv_seq_kernel(
    const void* __restrict__ seq, bf16* __restrict__ seqb,
    const int* __restrict__ flags)
{
  int flag = flags[0];
  long row = blockIdx.x;
#pragma unroll
  for (int i = 0; i < 3; i++) {
    long e = row * Dd + threadIdx.x + i * 256;
    seqb[e] = __float2bfloat16(ldg_any(seq, e, flag));
  }
}

// ---------- generic convert to bf16 (Wih) ----------
__global__ __launch_bounds__(256) void convert_kernel(
    const void* __restrict__ src, bf16* __restrict__ dst, long n,
    const int* __restrict__ flags)
{
  int flag = flags[0];
  long i = (long)blockIdx.x * 256 + threadIdx.x;
  if (i < n) dst[i] = __float2bfloat16(ldg_any(src, i, flag));
}

// ---------- small precomputes: Qsmall[11][7][768], embW[2][7][768], qmask7 ----------
__global__ __launch_bounds__(256) void smalls_kernel(
    const void* __restrict__ emb, const void* __restrict__ Wq,
    const void* __restrict__ bq, const void* __restrict__ Wih,
    float* __restrict__ Qsmall, float* __restrict__ embW,
    float* __restrict__ qmask7, const int* __restrict__ flags)
{
  int flag = flags[0];
  __shared__ float embsh[7 * 768];
  int z = blockIdx.y, chunk = blockIdx.x, tid = threadIdx.x;
  for (int i = tid; i < 7 * 768; i += 256) embsh[i] = ldg_any(emb, i, flag);
  __syncthreads();
  int n = chunk * 256 + tid;
  float acc[7] = {};
  if (z < NATT) {
    long base = (long)z * WSLICE;
    for (int e = 0; e < Dd; e++) {
      float wv = ldg_any(Wq, base + (long)e * Dd + n, flag);
#pragma unroll
      for (int l = 0; l < 7; l++) acc[l] += embsh[l * 768 + e] * wv;
    }
    float bv = ldg_any(bq, z * Dd + n, flag);
#pragma unroll
    for (int l = 0; l < 7; l++)
      Qsmall[((long)z * 7 + l) * Dd + n] = fmaxf(acc[l] + bv, 0.f);
  } else {
    int dir = z - NATT;
    long base = (long)dir * WSLICE + (long)n * Dd;
    for (int e = 0; e < Dd; e++) {
      float wv = ldg_any(Wih, base + e, flag);
#pragma unroll
      for (int l = 0; l < 7; l++) acc[l] += embsh[l * 768 + e] * wv;
    }
#pragma unroll
    for (int l = 0; l < 7; l++) embW[((long)dir * 7 + l) * Dd + n] = acc[l];
    if (z == NATT && chunk == 0 && tid < 7) {
      float s = 0.f;
      for (int e = 0; e < Dd; e++) s += embsh[tid * 768 + e];
      qmask7[tid] = (s != 0.f) ? 1.f : 0.f;
    }
  }
}

// ---------- transpose Wk/Wv branch slices to [N][K] bf16 ----------
__global__ __launch_bounds__(256) void transpose2_kernel(
    const void* __restrict__ Wk, const void* __restrict__ Wv,
    bf16* __restrict__ WT, const int* __restrict__ flags)
{
  int flag = flags[0];
  __shared__ float tile[32][33];
  int z = blockIdx.z;
  int m = z >> 1, wsel = z & 1;
  const void* src = wsel ? Wv : Wk;
  long off = (long)m * WSLICE;
  bf16* dst = WT + (long)z * WSLICE;
  int kk0 = blockIdx.y * 32, n0 = blockIdx.x * 32;
  int tx = threadIdx.x & 31, ty = threadIdx.x >> 5;
#pragma unroll
  for (int i = 0; i < 4; i++)
    tile[ty + i * 8][tx] = ldg_any(src, off + (long)(kk0 + ty + i * 8) * Dd + n0 + tx, flag);
  __syncthreads();
#pragma unroll
  for (int i = 0; i < 4; i++)
    dst[(long)(n0 + ty + i * 8) * Dd + kk0 + tx] = __float2bfloat16(tile[tx][ty + i * 8]);
}

// ---------- MFMA GEMM core: C = epi(scale*A@B^T) ----------
// cMode: 0=bf16, 2=fp32, 3=fp16, 4=fp16 transposed (C[col*ldC+row])
__device__ __forceinline__ void gemm_mfma_core(
    const bf16* __restrict__ Ab, long ldA,
    const bf16* __restrict__ Bbp, long ldB,
    bf16* As, bf16* Bs, int bm, int bn, int K,
    const void* bias, long bOff,
    void* C, long ldC, int cMode,
    float scale, int relu, int fflag)
{
  int tid = threadIdx.x;
  int lane = tid & 63, w = tid >> 6;
  int mo = (w & 1) * 64, no = (w >> 1) * 64;
  int l15 = lane & 15, q4 = lane >> 4;
  int gr = lane >> 2;
  int gs = (lane & 3) * 8;
  const bf16* aS0 = Ab + (long)(bm + w * 16 + gr) * ldA + gs;
  const bf16* aS1 = aS0 + 64 * ldA;
  const bf16* bS0 = Bbp + (long)(bn + w * 16 + gr) * ldB + gs;
  const bf16* bS1 = bS0 + 64 * ldB;
  bf16* aD0 = As + w * 512;
  bf16* aD1 = As + 2048 + w * 512;
  bf16* bD0 = Bs + w * 512;
  bf16* bD1 = Bs + 2048 + w * 512;

  f32x4 acc[4][4];
#pragma unroll
  for (int i = 0; i < 4; i++)
#pragma unroll
    for (int j = 0; j < 4; j++)
#pragma unroll
      for (int r = 0; r < 4; r++) acc[i][j][r] = 0.f;

  for (int k0 = 0; k0 < K; k0 += 32) {
    load_lds16(aS0, aD0);
    load_lds16(aS1, aD1);
    load_lds16(bS0, bD0);
    load_lds16(bS1, bD1);
    aS0 += 32; aS1 += 32; bS0 += 32; bS1 += 32;
    __syncthreads();
    short8 af[4], bfv[4];
#pragma unroll
    for (int i = 0; i < 4; i++)
      af[i] = *(const short8*)(As + (mo + i * 16 + l15) * 32 + q4 * 8);
#pragma unroll
    for (int j = 0; j < 4; j++)
      bfv[j] = *(const short8*)(Bs + (no + j * 16 + l15) * 32 + q4 * 8);
#pragma unroll
    for (int i = 0; i < 4; i++)
#pragma unroll
      for (int j = 0; j < 4; j++)
        acc[i][j] = __builtin_amdgcn_mfma_f32_16x16x32_bf16(af[i], bfv[j], acc[i][j], 0, 0, 0);
    __syncthreads();
  }

  float bsv[4];
#pragma unroll
  for (int j = 0; j < 4; j++) {
    int colg = bn + no + j * 16 + l15;
    bsv[j] = bias ? ldg_any(bias, bOff + colg, fflag) : 0.f;
  }
#pragma unroll
  for (int i = 0; i < 4; i++) {
#pragma unroll
    for (int j = 0; j < 4; j++) {
      int colg = bn + no + j * 16 + l15;
      if (cMode == 4) {
        int rowg0 = bm + mo + i * 16 + q4 * 4;
        ushort4 pk;
        unsigned short tmp[4];
#pragma unroll
        for (int r = 0; r < 4; r++) {
          float v = acc[i][j][r] * scale + bsv[j];
          if (relu) v = fmaxf(v, 0.f);
          tmp[r] = f2h(v);
        }
        pk.x = tmp[0]; pk.y = tmp[1]; pk.z = tmp[2]; pk.w = tmp[3];
        *(ushort4*)((unsigned short*)C + (long)colg * ldC + rowg0) = pk;
      } else {
#pragma unroll
        for (int r = 0; r < 4; r++) {
          int rowg = bm + mo + i * 16 + q4 * 4 + r;
          float v = acc[i][j][r] * scale + bsv[j];
          if (relu) v = fmaxf(v, 0.f);
          long off2 = (long)rowg * ldC + colg;
          if (cMode == 2)      ((float*)C)[off2] = v;
          else if (cMode == 3) ((unsigned short*)C)[off2] = f2h(v);
          else                 ((bf16*)C)[off2] = __float2bfloat16(v);
        }
      }
    }
  }
}

// ---------- K/V projections (fp16 out), z = m*2 + {0:K,1:V} ----------
__global__ __launch_bounds__(256, 2) void proj_kernel(
    const bf16* __restrict__ seqb, const bf16* __restrict__ WT,
    const void* __restrict__ bk, const void* __restrict__ bv,
    unsigned short* __restrict__ Kb, unsigned short* __restrict__ Vt,
    const int* __restrict__ flags)
{
  __shared__ __align__(16) bf16 As[4096];
  __shared__ __align__(16) bf16 Bs[4096];
  int z = blockIdx.z;
  int m = z >> 1, wsel = z & 1;
  const bf16* B = WT + (long)z * WSLICE;
  if (wsel == 0) {
    gemm_mfma_core(seqb, Dd, B, Dd, As, Bs, blockIdx.y * 128, blockIdx.x * 128, Dd,
                   bk, (long)m * Dd, Kb + (long)m * 4096 * Dd, Dd, 3, 1.f, 1, flags[0]);
  } else {
    gemm_mfma_core(seqb, Dd, B, Dd, As, Bs, blockIdx.y * 128, blockIdx.x * 128, Dd,
                   bv, (long)m * Dd, Vt + (long)m * Dd * 4096, 4096, 4, 1.f, 1, flags[0]);
  }
}

// ---------- seqW = seq @ Wih^T + bih (bf16), z = dir ----------
__global__ __launch_bounds__(256, 2) void seqw_kernel(
    const bf16* __restrict__ seqb, const bf16* __restrict__ WihB,
    const void* __restrict__ bih, bf16* __restrict__ seqW,
    const int* __restrict__ flags)
{
  __shared__ __align__(16) bf16 As[4096];
  __shared__ __align__(16) bf16 Bs[4096];
  int dir = blockIdx.z;
  gemm_mfma_core(seqb, Dd, WihB + (long)dir * WSLICE, Dd, As, Bs,
                 blockIdx.y * 128, blockIdx.x * 128, Dd,
                 bih, (long)dir * Dd, seqW + (long)dir * 4096 * Dd, Dd, 0,
                 1.f, 0, flags[0]);
}

// ---------- PVW = outsmall @ Wih^T (fp32), z = dir ----------
__global__ __launch_bounds__(256, 2) void pvw_kernel(
    const bf16* __restrict__ outsmall, const bf16* __restrict__ WihB,
    float* __restrict__ PVW, const int* __restrict__ flags)
{
  __shared__ __align__(16) bf16 As[4096];
  __shared__ __align__(16) bf16 Bs[4096];
  int dir = blockIdx.z;
  gemm_mfma_core(outsmall, Dd, WihB + (long)dir * WSLICE, Dd, As, Bs,
                 blockIdx.y * 128, blockIdx.x * 128, Dd,
                 nullptr, 0, PVW + (long)dir * 640 * Dd, Dd, 2, 1.f, 0, flags[0]);
}

// ---------- fused scores+softmax+mask+PV per (k,b) ----------
__global__ __launch_bounds__(512, 2) void attn_kernel(
    const unsigned short* __restrict__ Kb, const unsigned short* __restrict__ Vt,
    const float* __restrict__ Qsmall, const float* __restrict__ qmask7,
    bf16* __restrict__ outsmall, float scl)
{
  int blk = blockIdx.x;  // k*8+b
  int k = blk >> 3, b = blk & 7;
  int tid = threadIdx.x;
  int lane = tid & 63, w = tid >> 6;
  __shared__ unsigned qs[7][384];          // Q as fp16 pairs
  __shared__ unsigned short ash[7][512];   // attn fp16
  __shared__ float wred[8][7];
  __shared__ float gred[7];
  __shared__ float finv[7];
  for (int i = tid; i < 7 * 384; i += 512) {
    int l = i / 384, e2 = i - l * 384;
    const float* qp = Qsmall + ((long)k * 7 + l) * Dd + 2 * e2;
    qs[l][e2] = packh2(qp[0], qp[1]);
  }
  __syncthreads();
  // scores for row m = tid
  const uint4* Krow = (const uint4*)(Kb + ((long)k * 4096 + b * 512 + tid) * Dd);
  float sc[7] = {};
  for (int e8 = 0; e8 < 96; e8++) {
    uint4 kv = Krow[e8];
#pragma unroll
    for (int l = 0; l < 7; l++) {
      sc[l] = dot2u(qs[l][e8 * 4],     kv.x, sc[l]);
      sc[l] = dot2u(qs[l][e8 * 4 + 1], kv.y, sc[l]);
      sc[l] = dot2u(qs[l][e8 * 4 + 2], kv.z, sc[l]);
      sc[l] = dot2u(qs[l][e8 * 4 + 3], kv.w, sc[l]);
    }
  }
#pragma unroll
  for (int l = 0; l < 7; l++) sc[l] *= scl;
  // max over m
#pragma unroll
  for (int l = 0; l < 7; l++) {
    float v = sc[l];
    for (int o = 32; o > 0; o >>= 1) v = fmaxf(v, __shfl_down(v, o));
    if (lane == 0) wred[w][l] = v;
  }
  __syncthreads();
  if (tid < 7) {
    float m = wred[0][tid];
#pragma unroll
    for (int i = 1; i < 8; i++) m = fmaxf(m, wred[i][tid]);
    gred[tid] = m;
  }
  __syncthreads();
  float ev[7];
#pragma unroll
  for (int l = 0; l < 7; l++) {
    ev[l] = __expf(sc[l] - gred[l]);
    float v = ev[l];
    for (int o = 32; o > 0; o >>= 1) v += __shfl_down(v, o);
    if (lane == 0) wred[w][l] = v;
  }
  __syncthreads();
  if (tid < 7) {
    float s = 0.f;
#pragma unroll
    for (int i = 0; i < 8; i++) s += wred[i][tid];
    finv[tid] = qmask7[tid] / s;
  }
  __syncthreads();
#pragma unroll
  for (int l = 0; l < 7; l++) ash[l][tid] = f2h(ev[l] * finv[l]);
  __syncthreads();
  // PV: out[l][n] = sum_m attn[l][m] * V[n][m]
  for (int rep = 0; rep < 2; rep++) {
    int n = tid + rep * 512;
    if (n >= Dd) break;
    const uint4* Vrow = (const uint4*)(Vt + ((long)k * Dd + n) * 4096 + b * 512);
    float acc[7] = {};
    for (int m8 = 0; m8 < 64; m8++) {
      uint4 vv = Vrow[m8];
#pragma unroll
      for (int l = 0; l < 7; l++) {
        const unsigned* ap = (const unsigned*)&ash[l][0];
        acc[l] = dot2u(ap[m8 * 4],     vv.x, acc[l]);
        acc[l] = dot2u(ap[m8 * 4 + 1], vv.y, acc[l]);
        acc[l] = dot2u(ap[m8 * 4 + 2], vv.z, acc[l]);
        acc[l] = dot2u(ap[m8 * 4 + 3], vv.w, acc[l]);
      }
    }
#pragma unroll
    for (int l = 0; l < 7; l++)
      outsmall[((long)blk * 7 + l) * Dd + n] = __float2bfloat16(acc[l]);
  }
}

// ---------- GRU: 768 threads (gate g, channel c), weights VGPR-resident ----------
__global__ __launch_bounds__(768, 3) void gru_kernel(
    const bf16* __restrict__ seqW,   // [2][4096][768] bf16, includes bih
    const float* __restrict__ PVW,   // [2][640][768]
    const float* __restrict__ embW,  // [2][7][768]
    const void* __restrict__ labels,
    const void* __restrict__ Whh, const void* __restrict__ bhh,
    float* __restrict__ hbuf, const int* __restrict__ flags)
{
  int flag = flags[0], lflag = flags[1];
  int idx = blockIdx.x;
  int dir = idx / 88, n = idx - dir * 88;
  int b = n & 7;
  int tid = threadIdx.x;
  int g = tid >> 8, c = tid & 255;

  // full Whh row (g*256+c): 256 cols -> 128 fp16x2 regs
  unsigned w[128];
  {
    long rowBase = ((long)dir * Dd + g * 256 + c) * Hh;
    if (flag) {
      const float4* s4 = (const float4*)((const float*)Whh + rowBase);
#pragma unroll
      for (int i = 0; i < 64; i++) {
        float4 v = s4[i];
        w[2 * i]     = packh2(v.x, v.y);
        w[2 * i + 1] = packh2(v.z, v.w);
      }
    } else {
      const uint4* s4 = (const uint4*)((const bf16*)Whh + rowBase);
#pragma unroll
      for (int i = 0; i < 32; i++) {
        uint4 v = s4[i];
        w[4 * i]     = packh2(blo(v.x), bhi(v.x));
        w[4 * i + 1] = packh2(blo(v.y), bhi(v.y));
        w[4 * i + 2] = packh2(blo(v.z), bhi(v.z));
        w[4 * i + 3] = packh2(blo(v.w), bhi(v.w));
      }
    }
  }
  float bh = ldg_any(bhh, dir * Dd + g * 256 + c, flag);

  __shared__ float rowsh[7 * 768];          // PVW+embW per label
  __shared__ int labsh[512];
  __shared__ __align__(16) unsigned short hsh[256];
  __shared__ float gsh[768];
  __shared__ unsigned short xsh[2][768];

  for (int i = tid; i < 7 * 768; i += 768)
    rowsh[i] = PVW[((long)dir * 640 + n * 7 + (i / 768)) * Dd + (i % 768)]
             + embW[((long)dir * 7 + (i / 768)) * Dd + (i % 768)];
  if (tid < 512)
    labsh[tid] = lflag ? (int)((const long long*)labels)[b * 512 + tid]
                       : ((const int*)labels)[b * 512 + tid];
  if (tid < 256) hsh[tid] = 0;
  const unsigned short* sw = (const unsigned short*)seqW;
  long swBase = ((long)dir * 4096 + b * 512) * Dd;
  {
    int t0 = dir ? 511 : 0;
    xsh[0][tid] = sw[swBase + (long)t0 * Dd + tid];
  }
  int t1 = dir ? 510 : 1;
  unsigned short xpend = sw[swBase + (long)t1 * Dd + tid];
  __syncthreads();

  float hprev = 0.f;
  const uint4* hp = (const uint4*)hsh;
  for (int tt = 0; tt < Ss; tt++) {
    int t = dir ? 511 - tt : tt;
    int tt2 = (tt + 2 < Ss) ? tt + 2 : Ss - 1;
    int t2 = dir ? 511 - tt2 : tt2;
    unsigned short xnew = sw[swBase + (long)t2 * Dd + tid];
    float a = 0.f;
#pragma unroll
    for (int jj = 0; jj < 32; jj++) {
      uint4 hv = hp[jj];
      a = dot2u(w[4 * jj],     hv.x, a);
      a = dot2u(w[4 * jj + 1], hv.y, a);
      a = dot2u(w[4 * jj + 2], hv.z, a);
      a = dot2u(w[4 * jj + 3], hv.w, a);
    }
    gsh[tid] = a + bh;
    xsh[(tt + 1) & 1][tid] = xpend;
    __syncthreads();
    if (tid < 256) {
      int cb = tt & 1;
      const float* rs = rowsh + labsh[t] * 768;
      float xr = rs[tid]       + b2f(xsh[cb][tid]);
      float xz = rs[tid + 256] + b2f(xsh[cb][tid + 256]);
      float xn = rs[tid + 512] + b2f(xsh[cb][tid + 512]);
      float r = 1.f / (1.f + __expf(-(xr + gsh[tid])));
      float z = 1.f / (1.f + __expf(-(xz + gsh[tid + 256])));
      float targ = xn + r * gsh[tid + 512];
      float e2 = __expf(2.f * targ);
      float nn2 = 1.f - 2.f / (e2 + 1.f);
      float hnew = (1.f - z) * nn2 + z * hprev;
      hprev = hnew;
      hsh[tid] = f2h(hnew);
    }
    __syncthreads();
    xpend = xnew;
  }
  if (tid < 256) hbuf[((long)(dir * 88 + n)) * Hh + tid] = hprev;
}

// ---------- final head ----------
__global__ __launch_bounds__(256) void head_kernel(
    const float* __restrict__ hbuf, const void* __restrict__ W1,
    const void* __restrict__ b1, void* __restrict__ out,
    const int* __restrict__ flags)
{
  int flag = flags[0];
  int n = blockIdx.x;
  int c = threadIdx.x;
  float v = hbuf[(long)n * Hh + c] * ldg_any(W1, c, flag)
          + hbuf[(long)(88 + n) * Hh + c] * ldg_any(W1, 256 + c, flag);
  for (int o = 32; o > 0; o >>= 1) v += __shfl_down(v, o);
  __shared__ float red[4];
  if ((c & 63) == 0) red[c >> 6] = v;
  __syncthreads();
  if (c == 0) {
    float s = red[0] + red[1] + red[2] + red[3] + ldg_any(b1, 0, flag);
    float sig = 1.f / (1.f + __expf(-s));
    int k = n / Bb, b = n - k * Bb;
    int o = b * NATT + k;
    if (flag) ((float*)out)[o] = sig;
    else      stf((bf16*)out + o, sig);
  }
}

extern "C" void kernel_launch(void* const* d_in, const int* in_sizes, int n_in,
                              void* d_out, int out_size, void* d_ws, size_t ws_size,
                              hipStream_t stream) {
  const void* labels = d_in[0];
  const void* seq  = d_in[1];
  const void* emb  = d_in[2];
  const void* Wq   = d_in[3];
  const void* bq   = d_in[4];
  const void* Wk   = d_in[5];
  const void* bk   = d_in[6];
  const void* Wv   = d_in[7];
  const void* bv   = d_in[8];
  const void* Wih  = d_in[9];
  const void* Whh  = d_in[10];
  const void* bih  = d_in[11];
  const void* bhh  = d_in[12];
  const void* W1   = d_in[13];
  const void* b1   = d_in[14];

  char* p = (char*)d_ws;
  size_t off = 0;
  auto alloc = [&](size_t bytes) -> void* {
    void* r = p + off; off += (bytes + 255) & ~(size_t)255; return r;
  };
  int*    flags  = (int*)alloc(2 * sizeof(int));
  bf16*   seqb   = (bf16*)alloc(4096UL * 768 * 2);
  float*  qmask7 = (float*)alloc(7 * 4);
  float*  Qsmall = (float*)alloc(11UL * 7 * 768 * 4);
  float*  embW   = (float*)alloc(2UL * 7 * 768 * 4);
  bf16*   WihB   = (bf16*)alloc(2UL * WSLICE * 2);
  bf16*   WT     = (bf16*)alloc(22UL * WSLICE * 2);
  unsigned short* Kb = (unsigned short*)alloc(11UL * 4096 * 768 * 2);
  unsigned short* Vt = (unsigned short*)alloc(11UL * 768 * 4096 * 2);
  bf16*   outsm  = (bf16*)alloc(640UL * 768 * 2);
  float*  PVW    = (float*)alloc(2UL * 640 * 768 * 4);
  bf16*   seqW   = (bf16*)alloc(2UL * 4096 * 768 * 2);
  float*  hbuf   = (float*)alloc(2UL * 88 * 256 * 4);
  if (off > ws_size) return;

  probe_kernel<<<1, 64, 0, stream>>>((const unsigned short*)seq,
                                     (const unsigned*)labels, flags);
  conv_seq_kernel<<<4096, 256, 0, stream>>>(seq, seqb, flags);
  convert_kernel<<<(int)((2 * WSLICE + 255) / 256), 256, 0, stream>>>(
      Wih, WihB, 2L * WSLICE, flags);
  smalls_kernel<<<dim3(3, 13), 256, 0, stream>>>(
      emb, Wq, bq, Wih, Qsmall, embW, qmask7, flags);
  transpose2_kernel<<<dim3(24, 24, 22), 256, 0, stream>>>(Wk, Wv, WT, flags);
  proj_kernel<<<dim3(6, 32, 22), 256, 0, stream>>>(
      seqb, WT, bk, bv, Kb, Vt, flags);
  seqw_kernel<<<dim3(6, 32, 2), 256, 0, stream>>>(seqb, WihB, bih, seqW, flags);
  const float scl = 1.f / sqrtf(768.f);
  attn_kernel<<<88, 512, 0, stream>>>(Kb, Vt, Qsmall, qmask7, outsm, scl);
  pvw_kernel<<<dim3(6, 5, 2), 256, 0, stream>>>(outsm, WihB, PVW, flags);
  gru_kernel<<<176, 768, 0, stream>>>(seqW, PVW, embW, labels, Whh, bhh, hbuf, flags);
  head_kernel<<<88, 256, 0, stream>>>(hbuf, W1, b1, d_out, flags);
}

// Round 7
// 1177.001 us; speedup vs baseline: 21.9421x; 1.0256x over previous
//
#include <hip/hip_runtime.h>
#include <hip/hip_bf16.h>
#include <hip/hip_fp16.h>
#include <math.h>

typedef __hip_bfloat16 bf16;
typedef __attribute__((ext_vector_type(8))) short short8;
typedef __attribute__((ext_vector_type(4))) float f32x4;

#define NATT 11
#define Bb 8
#define Ss 512
#define Dd 768
#define Hh 256
#define WSLICE 589824L  // 768*768

__device__ __forceinline__ void stf(float* p, float v) { *p = v; }
__device__ __forceinline__ void stf(bf16* p, float v) { *p = __float2bfloat16(v); }

__device__ __forceinline__ float blo(unsigned u) { return __uint_as_float(u << 16); }
__device__ __forceinline__ float bhi(unsigned u) { return __uint_as_float(u & 0xffff0000u); }
__device__ __forceinline__ float b2f(unsigned short u) { return __uint_as_float(((unsigned)u) << 16); }

__device__ __forceinline__ float ldg_any(const void* base, long idx, int flag) {
  if (flag) return ((const float*)base)[idx];
  return __bfloat162float(((const bf16*)base)[idx]);
}

__device__ __forceinline__ unsigned packh2(float a, float b) {
  __half2 hh = __floats2half2_rn(a, b);
  return __builtin_bit_cast(unsigned, hh);
}
__device__ __forceinline__ unsigned short f2h(float v) {
  __half h = __float2half(v);
  return __builtin_bit_cast(unsigned short, h);
}

typedef _Float16 f16x2 __attribute__((ext_vector_type(2)));

__device__ __forceinline__ float dot2u(unsigned a, unsigned b, float c) {
#if __has_builtin(__builtin_amdgcn_fdot2)
  return __builtin_amdgcn_fdot2(__builtin_bit_cast(f16x2, a),
                                __builtin_bit_cast(f16x2, b), c, false);
#else
  __half2 ah = __builtin_bit_cast(__half2, a);
  __half2 bh = __builtin_bit_cast(__half2, b);
  float2 af = __half22float2(ah), bf = __half22float2(bh);
  return c + af.x * bf.x + af.y * bf.y;
#endif
}

// sum across a lane-quad using DPP quad_perm (VALU only, no LDS)
__device__ __forceinline__ float quad_sum(float v) {
#if __has_builtin(__builtin_amdgcn_update_dpp)
  int y = __builtin_amdgcn_update_dpp(0, __builtin_bit_cast(int, v), 0xB1, 0xF, 0xF, true);
  v += __builtin_bit_cast(float, y);
  y = __builtin_amdgcn_update_dpp(0, __builtin_bit_cast(int, v), 0x4E, 0xF, 0xF, true);
  v += __builtin_bit_cast(float, y);
  return v;
#else
  v += __shfl_xor(v, 1);
  v += __shfl_xor(v, 2);
  return v;
#endif
}

__device__ __forceinline__ void load_lds16(const void* g, void* l) {
  __builtin_amdgcn_global_load_lds(
      (const __attribute__((address_space(1))) unsigned int*)g,
      (__attribute__((address_space(3))) unsigned int*)l, 16, 0, 0);
}

// ---------- dtype probe ----------
__global__ __launch_bounds__(64) void probe_kernel(
    const unsigned short* __restrict__ sequ, const unsigned* __restrict__ labu,
    int* __restrict__ flags)
{
  int t = threadIdx.x;
  int wild = 0;
#pragma unroll
  for (int i = 0; i < 4; i++) {
    unsigned short v = sequ[t + i * 64];
    int e = (v >> 7) & 0xFF;
    if (e < 90 || e > 160) wild++;
  }
  int nzodd = 0;
#pragma unroll
  for (int i = 0; i < 2; i++) {
    unsigned w = labu[(t + i * 64) * 2 + 1];
    if (w != 0) nzodd++;
  }
  for (int o = 32; o > 0; o >>= 1) {
    wild  += __shfl_down(wild, o);
    nzodd += __shfl_down(nzodd, o);
  }
  if (t == 0) {
    flags[0] = (wild > 32) ? 1 : 0;
    flags[1] = (nzodd == 0) ? 1 : 0;
  }
}

// ---------- seq -> bf16 ----------
__global__ __launch_bounds__(256) void conv_seq_kernel(
    const void* __restrict__ seq, bf16* __restrict__ seqb,
    const int* __restrict__ flags)
{
  int flag = flags[0];
  long row = blockIdx.x;
#pragma unroll
  for (int i = 0; i < 3; i++) {
    long e = row * Dd + threadIdx.x + i * 256;
    seqb[e] = __float2bfloat16(ldg_any(seq, e, flag));
  }
}

// ---------- generic convert to bf16 (Wih) ----------
__global__ __launch_bounds__(256) void convert_kernel(
    const void* __restrict__ src, bf16* __restrict__ dst, long n,
    const int* __restrict__ flags)
{
  int flag = flags[0];
  long i = (long)blockIdx.x * 256 + threadIdx.x;
  if (i < n) dst[i] = __float2bfloat16(ldg_any(src, i, flag));
}

// ---------- Qsmall[11][7][768] = relu(emb7 @ Wq + bq) ----------
__global__ __launch_bounds__(256) void smalls_kernel(
    const void* __restrict__ emb, const void* __restrict__ Wq,
    const void* __restrict__ bq, float* __restrict__ Qsmall,
    const int* __restrict__ flags)
{
  int flag = flags[0];
  __shared__ float embsh[7 * 768];
  int z = blockIdx.y, chunk = blockIdx.x, tid = threadIdx.x;
  for (int i = tid; i < 7 * 768; i += 256) embsh[i] = ldg_any(emb, i, flag);
  __syncthreads();
  int n = chunk * 256 + tid;
  float acc[7] = {};
  long base = (long)z * WSLICE;
  for (int e = 0; e < Dd; e++) {
    float wv = ldg_any(Wq, base + (long)e * Dd + n, flag);
#pragma unroll
    for (int l = 0; l < 7; l++) acc[l] += embsh[l * 768 + e] * wv;
  }
  float bv = ldg_any(bq, z * Dd + n, flag);
#pragma unroll
  for (int l = 0; l < 7; l++)
    Qsmall[((long)z * 7 + l) * Dd + n] = fmaxf(acc[l] + bv, 0.f);
}

// ---------- emb rows -> outsm[640+l] (bf16) + qmask7 ----------
__global__ __launch_bounds__(256) void emb_copy_kernel(
    const void* __restrict__ emb, bf16* __restrict__ outsm,
    float* __restrict__ qmask7, const int* __restrict__ flags)
{
  int flag = flags[0];
  int l = blockIdx.x;   // 0..6
  int t = threadIdx.x;
  float s = 0.f;
#pragma unroll
  for (int i = 0; i < 3; i++) {
    int e = t + i * 256;
    float v = ldg_any(emb, (long)l * Dd + e, flag);
    outsm[(long)(640 + l) * Dd + e] = __float2bfloat16(v);
    s += v;
  }
  for (int o = 32; o > 0; o >>= 1) s += __shfl_down(s, o);
  __shared__ float red[4];
  if ((t & 63) == 0) red[t >> 6] = s;
  __syncthreads();
  if (t == 0) {
    float tot = red[0] + red[1] + red[2] + red[3];
    qmask7[l] = (tot != 0.f) ? 1.f : 0.f;
  }
}

// ---------- transpose Wk/Wv branch slices to [N][K] bf16 ----------
__global__ __launch_bounds__(256) void transpose2_kernel(
    const void* __restrict__ Wk, const void* __restrict__ Wv,
    bf16* __restrict__ WT, const int* __restrict__ flags)
{
  int flag = flags[0];
  __shared__ float tile[32][33];
  int z = blockIdx.z;
  int m = z >> 1, wsel = z & 1;
  const void* src = wsel ? Wv : Wk;
  long off = (long)m * WSLICE;
  bf16* dst = WT + (long)z * WSLICE;
  int kk0 = blockIdx.y * 32, n0 = blockIdx.x * 32;
  int tx = threadIdx.x & 31, ty = threadIdx.x >> 5;
#pragma unroll
  for (int i = 0; i < 4; i++)
    tile[ty + i * 8][tx] = ldg_any(src, off + (long)(kk0 + ty + i * 8) * Dd + n0 + tx, flag);
  __syncthreads();
#pragma unroll
  for (int i = 0; i < 4; i++)
    dst[(long)(n0 + ty + i * 8) * Dd + kk0 + tx] = __float2bfloat16(tile[tx][ty + i * 8]);
}

// ---------- MFMA GEMM core: C = epi(scale*A@B^T) ----------
// cMode: 0=bf16, 2=fp32, 3=fp16, 4=fp16 transposed (C[col*ldC+row])
__device__ __forceinline__ void gemm_mfma_core(
    const bf16* __restrict__ Ab, long ldA,
    const bf16* __restrict__ Bbp, long ldB,
    bf16* As, bf16* Bs, int bm, int bn, int K,
    const void* bias, long bOff,
    void* C, long ldC, int cMode,
    float scale, int relu, int fflag)
{
  int tid = threadIdx.x;
  int lane = tid & 63, w = tid >> 6;
  int mo = (w & 1) * 64, no = (w >> 1) * 64;
  int l15 = lane & 15, q4 = lane >> 4;
  int gr = lane >> 2;
  int gs = (lane & 3) * 8;
  const bf16* aS0 = Ab + (long)(bm + w * 16 + gr) * ldA + gs;
  const bf16* aS1 = aS0 + 64 * ldA;
  const bf16* bS0 = Bbp + (long)(bn + w * 16 + gr) * ldB + gs;
  const bf16* bS1 = bS0 + 64 * ldB;
  bf16* aD0 = As + w * 512;
  bf16* aD1 = As + 2048 + w * 512;
  bf16* bD0 = Bs + w * 512;
  bf16* bD1 = Bs + 2048 + w * 512;

  f32x4 acc[4][4];
#pragma unroll
  for (int i = 0; i < 4; i++)
#pragma unroll
    for (int j = 0; j < 4; j++)
#pragma unroll
      for (int r = 0; r < 4; r++) acc[i][j][r] = 0.f;

  for (int k0 = 0; k0 < K; k0 += 32) {
    load_lds16(aS0, aD0);
    load_lds16(aS1, aD1);
    load_lds16(bS0, bD0);
    load_lds16(bS1, bD1);
    aS0 += 32; aS1 += 32; bS0 += 32; bS1 += 32;
    __syncthreads();
    short8 af[4], bfv[4];
#pragma unroll
    for (int i = 0; i < 4; i++)
      af[i] = *(const short8*)(As + (mo + i * 16 + l15) * 32 + q4 * 8);
#pragma unroll
    for (int j = 0; j < 4; j++)
      bfv[j] = *(const short8*)(Bs + (no + j * 16 + l15) * 32 + q4 * 8);
#pragma unroll
    for (int i = 0; i < 4; i++)
#pragma unroll
      for (int j = 0; j < 4; j++)
        acc[i][j] = __builtin_amdgcn_mfma_f32_16x16x32_bf16(af[i], bfv[j], acc[i][j], 0, 0, 0);
    __syncthreads();
  }

  float bsv[4];
#pragma unroll
  for (int j = 0; j < 4; j++) {
    int colg = bn + no + j * 16 + l15;
    bsv[j] = bias ? ldg_any(bias, bOff + colg, fflag) : 0.f;
  }
#pragma unroll
  for (int i = 0; i < 4; i++) {
#pragma unroll
    for (int j = 0; j < 4; j++) {
      int colg = bn + no + j * 16 + l15;
      if (cMode == 4) {
        int rowg0 = bm + mo + i * 16 + q4 * 4;
        ushort4 pk;
        unsigned short tmp[4];
#pragma unroll
        for (int r = 0; r < 4; r++) {
          float v = acc[i][j][r] * scale + bsv[j];
          if (relu) v = fmaxf(v, 0.f);
          tmp[r] = f2h(v);
        }
        pk.x = tmp[0]; pk.y = tmp[1]; pk.z = tmp[2]; pk.w = tmp[3];
        *(ushort4*)((unsigned short*)C + (long)colg * ldC + rowg0) = pk;
      } else {
#pragma unroll
        for (int r = 0; r < 4; r++) {
          int rowg = bm + mo + i * 16 + q4 * 4 + r;
          float v = acc[i][j][r] * scale + bsv[j];
          if (relu) v = fmaxf(v, 0.f);
          long off2 = (long)rowg * ldC + colg;
          if (cMode == 2)      ((float*)C)[off2] = v;
          else if (cMode == 3) ((unsigned short*)C)[off2] = f2h(v);
          else                 ((bf16*)C)[off2] = __float2bfloat16(v);
        }
      }
    }
  }
}

// ---------- K/V projections (fp16 out), z = m*2 + {0:K,1:V} ----------
__global__ __launch_bounds__(256, 2) void proj_kernel(
    const bf16* __restrict__ seqb, const bf16* __restrict__ WT,
    const void* __restrict__ bk, const void* __restrict__ bv,
    unsigned short* __restrict__ Kb, unsigned short* __restrict__ Vt,
    const int* __restrict__ flags)
{
  __shared__ __align__(16) bf16 As[4096];
  __shared__ __align__(16) bf16 Bs[4096];
  int z = blockIdx.z;
  int m = z >> 1, wsel = z & 1;
  const bf16* B = WT + (long)z * WSLICE;
  if (wsel == 0) {
    gemm_mfma_core(seqb, Dd, B, Dd, As, Bs, blockIdx.y * 128, blockIdx.x * 128, Dd,
                   bk, (long)m * Dd, Kb + (long)m * 4096 * Dd, Dd, 3, 1.f, 1, flags[0]);
  } else {
    gemm_mfma_core(seqb, Dd, B, Dd, As, Bs, blockIdx.y * 128, blockIdx.x * 128, Dd,
                   bv, (long)m * Dd, Vt + (long)m * Dd * 4096, 4096, 4, 1.f, 1, flags[0]);
  }
}

// ---------- seqW = seq @ Wih^T + bih (bf16), z = dir ----------
__global__ __launch_bounds__(256, 2) void seqw_kernel(
    const bf16* __restrict__ seqb, const bf16* __restrict__ WihB,
    const void* __restrict__ bih, bf16* __restrict__ seqW,
    const int* __restrict__ flags)
{
  __shared__ __align__(16) bf16 As[4096];
  __shared__ __align__(16) bf16 Bs[4096];
  int dir = blockIdx.z;
  gemm_mfma_core(seqb, Dd, WihB + (long)dir * WSLICE, Dd, As, Bs,
                 blockIdx.y * 128, blockIdx.x * 128, Dd,
                 bih, (long)dir * Dd, seqW + (long)dir * 4096 * Dd, Dd, 0,
                 1.f, 0, flags[0]);
}

// ---------- PVW = outsm(768 rows incl emb @640) @ Wih^T (fp32), z = dir ----------
__global__ __launch_bounds__(256, 2) void pvw_kernel(
    const bf16* __restrict__ outsm, const bf16* __restrict__ WihB,
    float* __restrict__ PVW, const int* __restrict__ flags)
{
  __shared__ __align__(16) bf16 As[4096];
  __shared__ __align__(16) bf16 Bs[4096];
  int dir = blockIdx.z;
  gemm_mfma_core(outsm, Dd, WihB + (long)dir * WSLICE, Dd, As, Bs,
                 blockIdx.y * 128, blockIdx.x * 128, Dd,
                 nullptr, 0, PVW + (long)dir * 768 * Dd, Dd, 2, 1.f, 0, flags[0]);
}

// ---------- fused scores+softmax+mask+PV per (k,b) ----------
__global__ __launch_bounds__(512, 2) void attn_kernel(
    const unsigned short* __restrict__ Kb, const unsigned short* __restrict__ Vt,
    const float* __restrict__ Qsmall, const float* __restrict__ qmask7,
    bf16* __restrict__ outsm, float scl)
{
  int blk = blockIdx.x;  // k*8+b
  int k = blk >> 3, b = blk & 7;
  int tid = threadIdx.x;
  int lane = tid & 63, w = tid >> 6;
  __shared__ unsigned qs[7][384];
  __shared__ unsigned short ash[7][512];
  __shared__ float wred[8][7];
  __shared__ float gred[7];
  __shared__ float finv[7];
  for (int i = tid; i < 7 * 384; i += 512) {
    int l = i / 384, e2 = i - l * 384;
    const float* qp = Qsmall + ((long)k * 7 + l) * Dd + 2 * e2;
    qs[l][e2] = packh2(qp[0], qp[1]);
  }
  __syncthreads();
  const uint4* Krow = (const uint4*)(Kb + ((long)k * 4096 + b * 512 + tid) * Dd);
  float sc[7] = {};
  for (int e8 = 0; e8 < 96; e8++) {
    uint4 kv = Krow[e8];
#pragma unroll
    for (int l = 0; l < 7; l++) {
      sc[l] = dot2u(qs[l][e8 * 4],     kv.x, sc[l]);
      sc[l] = dot2u(qs[l][e8 * 4 + 1], kv.y, sc[l]);
      sc[l] = dot2u(qs[l][e8 * 4 + 2], kv.z, sc[l]);
      sc[l] = dot2u(qs[l][e8 * 4 + 3], kv.w, sc[l]);
    }
  }
#pragma unroll
  for (int l = 0; l < 7; l++) sc[l] *= scl;
#pragma unroll
  for (int l = 0; l < 7; l++) {
    float v = sc[l];
    for (int o = 32; o > 0; o >>= 1) v = fmaxf(v, __shfl_down(v, o));
    if (lane == 0) wred[w][l] = v;
  }
  __syncthreads();
  if (tid < 7) {
    float m = wred[0][tid];
#pragma unroll
    for (int i = 1; i < 8; i++) m = fmaxf(m, wred[i][tid]);
    gred[tid] = m;
  }
  __syncthreads();
  float ev[7];
#pragma unroll
  for (int l = 0; l < 7; l++) {
    ev[l] = __expf(sc[l] - gred[l]);
    float v = ev[l];
    for (int o = 32; o > 0; o >>= 1) v += __shfl_down(v, o);
    if (lane == 0) wred[w][l] = v;
  }
  __syncthreads();
  if (tid < 7) {
    float s = 0.f;
#pragma unroll
    for (int i = 0; i < 8; i++) s += wred[i][tid];
    finv[tid] = qmask7[tid] / s;
  }
  __syncthreads();
#pragma unroll
  for (int l = 0; l < 7; l++) ash[l][tid] = f2h(ev[l] * finv[l]);
  __syncthreads();
  for (int rep = 0; rep < 2; rep++) {
    int n = tid + rep * 512;
    if (n >= Dd) break;
    const uint4* Vrow = (const uint4*)(Vt + ((long)k * Dd + n) * 4096 + b * 512);
    float acc[7] = {};
    for (int m8 = 0; m8 < 64; m8++) {
      uint4 vv = Vrow[m8];
#pragma unroll
      for (int l = 0; l < 7; l++) {
        const unsigned* ap = (const unsigned*)&ash[l][0];
        acc[l] = dot2u(ap[m8 * 4],     vv.x, acc[l]);
        acc[l] = dot2u(ap[m8 * 4 + 1], vv.y, acc[l]);
        acc[l] = dot2u(ap[m8 * 4 + 2], vv.z, acc[l]);
        acc[l] = dot2u(ap[m8 * 4 + 3], vv.w, acc[l]);
      }
    }
#pragma unroll
    for (int l = 0; l < 7; l++)
      outsm[((long)blk * 7 + l) * Dd + n] = __float2bfloat16(acc[l]);
  }
}

// ---------- GRU v3: 512 thr = (cg:128, q:4 k-quarters); 6 rows/thread in VGPRs;
// DPP quad reduction; h fp16 in padded LDS quarters; x via global prefetch ----------
__global__ __launch_bounds__(512, 2) void gru_kernel(
    const bf16* __restrict__ seqW,   // [2][4096][768], includes bih
    const float* __restrict__ PVW,   // [2][768][768]; rows n*7+l and 640+l(emb)
    const void* __restrict__ labels,
    const void* __restrict__ Whh, const void* __restrict__ bhh,
    float* __restrict__ hbuf, const int* __restrict__ flags)
{
  int flag = flags[0], lflag = flags[1];
  int idx = blockIdx.x;
  int dir = idx / 88, n = idx - dir * 88;
  int b = n & 7;
  int tid = threadIdx.x;
  int q = tid & 3, cg = tid >> 2;
  int hi = q >> 1;
  int ch = cg + hi * 128;
  int r0 = ch, r1 = 256 + ch, r2 = 512 + ch;

  // 6 rows × 64-half k-quarter, packed fp16x2 -> 192 VGPRs
  unsigned w[6][32];
#pragma unroll
  for (int s = 0; s < 6; s++) {
    int row = (s >> 1) * 256 + cg + (s & 1) * 128;
    long base = ((long)dir * Dd + row) * Hh + q * 64;
    if (flag) {
      const float4* s4 = (const float4*)((const float*)Whh + base);
#pragma unroll
      for (int i = 0; i < 16; i++) {
        float4 v = s4[i];
        w[s][2 * i]     = packh2(v.x, v.y);
        w[s][2 * i + 1] = packh2(v.z, v.w);
      }
    } else {
      const uint4* s4 = (const uint4*)((const bf16*)Whh + base);
#pragma unroll
      for (int i = 0; i < 8; i++) {
        uint4 v = s4[i];
        w[s][4 * i]     = packh2(blo(v.x), bhi(v.x));
        w[s][4 * i + 1] = packh2(blo(v.y), bhi(v.y));
        w[s][4 * i + 2] = packh2(blo(v.z), bhi(v.z));
        w[s][4 * i + 3] = packh2(blo(v.w), bhi(v.w));
      }
    }
  }
  float bh0 = ldg_any(bhh, dir * Dd + r0, flag);
  float bh1 = ldg_any(bhh, dir * Dd + r1, flag);
  float bh2 = ldg_any(bhh, dir * Dd + r2, flag);

  __shared__ float rowsh[7 * 768];
  __shared__ int labsh[512];
  __shared__ __align__(16) unsigned short hsh[4 * 72];  // padded quarters

  for (int i = tid; i < 7 * 768; i += 512) {
    int l = i / 768, row = i - l * 768;
    rowsh[i] = PVW[((long)dir * 768 + n * 7 + l) * Dd + row]
             + PVW[((long)dir * 768 + 640 + l) * Dd + row];
  }
  labsh[tid] = lflag ? (int)((const long long*)labels)[b * 512 + tid]
                     : ((const int*)labels)[b * 512 + tid];
  if (tid < 288) hsh[tid] = 0;
  __syncthreads();

  const unsigned short* swu = (const unsigned short*)seqW
                            + ((long)dir * 4096 + b * 512) * Dd;
  int t0 = dir ? 511 : 0, t1 = dir ? 510 : 1;
  unsigned short xc0 = swu[(long)t0 * Dd + r0];
  unsigned short xc1 = swu[(long)t0 * Dd + r1];
  unsigned short xc2 = swu[(long)t0 * Dd + r2];
  unsigned short xn0 = swu[(long)t1 * Dd + r0];
  unsigned short xn1 = swu[(long)t1 * Dd + r1];
  unsigned short xn2 = swu[(long)t1 * Dd + r2];

  float hprev = 0.f;
  const uint4* hq = (const uint4*)(hsh + q * 72);
  int hwaddr = (ch >> 6) * 72 + (ch & 63);
  for (int tt = 0; tt < Ss; tt++) {
    int t = dir ? 511 - tt : tt;
    int ttp = (tt + 2 < Ss) ? tt + 2 : Ss - 1;
    int tp = dir ? 511 - ttp : ttp;
    unsigned short xp0 = swu[(long)tp * Dd + r0];
    unsigned short xp1 = swu[(long)tp * Dd + r1];
    unsigned short xp2 = swu[(long)tp * Dd + r2];
    float a[6] = {};
#pragma unroll
    for (int jj = 0; jj < 8; jj++) {
      uint4 hv = hq[jj];
#pragma unroll
      for (int s = 0; s < 6; s++) {
        a[s] = dot2u(w[s][4 * jj],     hv.x, a[s]);
        a[s] = dot2u(w[s][4 * jj + 1], hv.y, a[s]);
        a[s] = dot2u(w[s][4 * jj + 2], hv.z, a[s]);
        a[s] = dot2u(w[s][4 * jj + 3], hv.w, a[s]);
      }
    }
    __syncthreads();   // all h reads done before writers update
#pragma unroll
    for (int s = 0; s < 6; s++) a[s] = quad_sum(a[s]);
    float ar = hi ? a[1] : a[0];
    float az = hi ? a[3] : a[2];
    float an = hi ? a[5] : a[4];
    int lab = labsh[t];
    const float* rs = rowsh + lab * 768;
    float xr = rs[r0] + b2f(xc0);
    float xz = rs[r1] + b2f(xc1);
    float xn = rs[r2] + b2f(xc2);
    float rg = 1.f / (1.f + __expf(-(xr + ar + bh0)));
    float zg = 1.f / (1.f + __expf(-(xz + az + bh1)));
    float targ = xn + rg * (an + bh2);
    float e2 = __expf(2.f * targ);
    float ng = 1.f - 2.f / (e2 + 1.f);
    float hnew = (1.f - zg) * ng + zg * hprev;
    hprev = hnew;
    if ((q & 1) == 0) hsh[hwaddr] = f2h(hnew);
    __syncthreads();
    xc0 = xn0; xc1 = xn1; xc2 = xn2;
    xn0 = xp0; xn1 = xp1; xn2 = xp2;
  }
  if ((q & 1) == 0) hbuf[((long)(dir * 88 + n)) * Hh + ch] = hprev;
}

// ---------- final head ----------
__global__ __launch_bounds__(256) void head_kernel(
    const float* __restrict__ hbuf, const void* __restrict__ W1,
    const void* __restrict__ b1, void* __restrict__ out,
    const int* __restrict__ flags)
{
  int flag = flags[0];
  int n = blockIdx.x;
  int c = threadIdx.x;
  float v = hbuf[(long)n * Hh + c] * ldg_any(W1, c, flag)
          + hbuf[(long)(88 + n) * Hh + c] * ldg_any(W1, 256 + c, flag);
  for (int o = 32; o > 0; o >>= 1) v += __shfl_down(v, o);
  __shared__ float red[4];
  if ((c & 63) == 0) red[c >> 6] = v;
  __syncthreads();
  if (c == 0) {
    float s = red[0] + red[1] + red[2] + red[3] + ldg_any(b1, 0, flag);
    float sig = 1.f / (1.f + __expf(-s));
    int k = n / Bb, b = n - k * Bb;
    int o = b * NATT + k;
    if (flag) ((float*)out)[o] = sig;
    else      stf((bf16*)out + o, sig);
  }
}

extern "C" void kernel_launch(void* const* d_in, const int* in_sizes, int n_in,
                              void* d_out, int out_size, void* d_ws, size_t ws_size,
                              hipStream_t stream) {
  const void* labels = d_in[0];
  const void* seq  = d_in[1];
  const void* emb  = d_in[2];
  const void* Wq   = d_in[3];
  const void* bq   = d_in[4];
  const void* Wk   = d_in[5];
  const void* bk   = d_in[6];
  const void* Wv   = d_in[7];
  const void* bv   = d_in[8];
  const void* Wih  = d_in[9];
  const void* Whh  = d_in[10];
  const void* bih  = d_in[11];
  const void* bhh  = d_in[12];
  const void* W1   = d_in[13];
  const void* b1   = d_in[14];

  char* p = (char*)d_ws;
  size_t off = 0;
  auto alloc = [&](size_t bytes) -> void* {
    void* r = p + off; off += (bytes + 255) & ~(size_t)255; return r;
  };
  int*    flags  = (int*)alloc(2 * sizeof(int));
  bf16*   seqb   = (bf16*)alloc(4096UL * 768 * 2);
  float*  qmask7 = (float*)alloc(7 * 4);
  float*  Qsmall = (float*)alloc(11UL * 7 * 768 * 4);
  bf16*   WihB   = (bf16*)alloc(2UL * WSLICE * 2);
  bf16*   WT     = (bf16*)alloc(22UL * WSLICE * 2);
  unsigned short* Kb = (unsigned short*)alloc(11UL * 4096 * 768 * 2);
  unsigned short* Vt = (unsigned short*)alloc(11UL * 768 * 4096 * 2);
  bf16*   outsm  = (bf16*)alloc(768UL * 768 * 2);   // 616 attn rows + emb @640..646
  float*  PVW    = (float*)alloc(2UL * 768 * 768 * 4);
  bf16*   seqW   = (bf16*)alloc(2UL * 4096 * 768 * 2);
  float*  hbuf   = (float*)alloc(2UL * 88 * 256 * 4);
  if (off > ws_size) return;

  probe_kernel<<<1, 64, 0, stream>>>((const unsigned short*)seq,
                                     (const unsigned*)labels, flags);
  conv_seq_kernel<<<4096, 256, 0, stream>>>(seq, seqb, flags);
  convert_kernel<<<(int)((2 * WSLICE + 255) / 256), 256, 0, stream>>>(
      Wih, WihB, 2L * WSLICE, flags);
  smalls_kernel<<<dim3(3, 11), 256, 0, stream>>>(emb, Wq, bq, Qsmall, flags);
  emb_copy_kernel<<<7, 256, 0, stream>>>(emb, outsm, qmask7, flags);
  transpose2_kernel<<<dim3(24, 24, 22), 256, 0, stream>>>(Wk, Wv, WT, flags);
  proj_kernel<<<dim3(6, 32, 22), 256, 0, stream>>>(
      seqb, WT, bk, bv, Kb, Vt, flags);
  seqw_kernel<<<dim3(6, 32, 2), 256, 0, stream>>>(seqb, WihB, bih, seqW, flags);
  const float scl = 1.f / sqrtf(768.f);
  attn_kernel<<<88, 512, 0, stream>>>(Kb, Vt, Qsmall, qmask7, outsm, scl);
  pvw_kernel<<<dim3(6, 6, 2), 256, 0, stream>>>(outsm, WihB, PVW, flags);
  gru_kernel<<<176, 512, 0, stream>>>(seqW, PVW, labels, Whh, bhh, hbuf, flags);
  head_kernel<<<88, 256, 0, stream>>>(hbuf, W1, b1, d_out, flags);
}